// Round 1
// baseline (2382.932 us; speedup 1.0000x reference)
//
#include <hip/hip_runtime.h>
#include <math.h>

// SparseViT forward, fp32, correctness-first implementation.
// B=2, N=577, DIM=512, H=8, DH=64, DEPTH=2, MLP=2048, NCLS=1000
// nc = ceil(577/4) = 145, ns = ceil(577/64) = 10

#define NTOK 577
#define DIMD 512
#define NH 8
#define DHD 64
#define NC 145
#define NSB 10
#define KSELD 4
#define SBD 64
#define CBD 16
#define CSD 4
#define SWD 32
#define MLPD 2048
#define NCLSD 1000
#define BATCH 2

// ---------------- patch embed + cls + pos ----------------
__global__ void patch_kernel(const float* __restrict__ img, const float* __restrict__ pw,
                             const float* __restrict__ pb, const float* __restrict__ pos,
                             const float* __restrict__ cls, float* __restrict__ x) {
  int idx = blockIdx.x * 256 + threadIdx.x;
  const int total = BATCH * NTOK * DIMD;
  if (idx >= total) return;
  int d = idx & (DIMD - 1);
  int i = (idx / DIMD) % NTOK;
  int b = idx / (DIMD * NTOK);
  float val;
  if (i == 0) {
    val = cls[d];
  } else {
    int p = i - 1;
    val = pb[d];
#pragma unroll
    for (int c = 0; c < 3; ++c)
      val += img[b * 3 * 576 + c * 576 + p] * pw[c * DIMD + d];
  }
  x[idx] = val + pos[i * DIMD + d];
}

// ---------------- layernorm (one block per row, DIM=512, 256 threads) ----------------
__global__ void ln_kernel(const float* __restrict__ x, const float* __restrict__ g,
                          const float* __restrict__ bb, float* __restrict__ out,
                          long rstride) {
  int row = blockIdx.x;
  const float* xr = x + (long)row * rstride;
  int t = threadIdx.x;
  float a = xr[t], c = xr[t + 256];
  __shared__ float s1[256], s2[256];
  s1[t] = a + c;
  s2[t] = a * a + c * c;
  __syncthreads();
  for (int off = 128; off > 0; off >>= 1) {
    if (t < off) { s1[t] += s1[t + off]; s2[t] += s2[t + off]; }
    __syncthreads();
  }
  float m = s1[0] * (1.0f / 512.0f);
  float var = s2[0] * (1.0f / 512.0f) - m * m;
  float r = rsqrtf(var + 1e-5f);
  out[(long)row * DIMD + t]       = (a - m) * r * g[t] + bb[t];
  out[(long)row * DIMD + t + 256] = (c - m) * r * g[t + 256] + bb[t + 256];
}

// ---------------- generic fp32 GEMM: C = act(A@B + bias) + resid ----------------
// act: 0=none, 1=gelu(tanh approx), 2=sigmoid.  K must be a multiple of 16.
__global__ void gemm_kernel(const float* __restrict__ A, const float* __restrict__ Bm,
                            const float* __restrict__ bias, const float* __restrict__ resid,
                            float* __restrict__ C, int M, int Nn, int K, int act) {
  __shared__ float As[16][17], Bs[16][17];
  int tx = threadIdx.x, ty = threadIdx.y;
  int row = blockIdx.y * 16 + ty;
  int col = blockIdx.x * 16 + tx;
  float acc = 0.f;
  for (int k0 = 0; k0 < K; k0 += 16) {
    As[ty][tx] = (row < M) ? A[(long)row * K + k0 + tx] : 0.f;
    Bs[ty][tx] = (col < Nn) ? Bm[(long)(k0 + ty) * Nn + col] : 0.f;
    __syncthreads();
#pragma unroll
    for (int kk = 0; kk < 16; ++kk) acc += As[ty][kk] * Bs[kk][tx];
    __syncthreads();
  }
  if (row < M && col < Nn) {
    if (bias) acc += bias[col];
    if (act == 1) {
      float u = 0.7978845608028654f * (acc + 0.044715f * acc * acc * acc);
      acc = 0.5f * acc * (1.f + tanhf(u));
    } else if (act == 2) {
      acc = 1.f / (1.f + expf(-acc));
    }
    if (resid) acc += resid[(long)row * Nn + col];
    C[(long)row * Nn + col] = acc;
  }
}

// ---------------- compressed K/V:  ck/cv[b,h,j,:] = (kw flat 1024) @ Wkc ----------------
__global__ void ckcv_kernel(const float* __restrict__ k, const float* __restrict__ v,
                            const float* __restrict__ kpe, const float* __restrict__ vpe,
                            const float* __restrict__ Wkc, const float* __restrict__ Wvc,
                            float* __restrict__ ck, float* __restrict__ cv) {
  int j = blockIdx.x % NC;
  int h = (blockIdx.x / NC) % NH;
  int b = blockIdx.x / (NC * NH);
  int lane = threadIdx.x;  // 0..63
  __shared__ float kw[CBD * DHD], vw[CBD * DHD];
#pragma unroll
  for (int t = 0; t < CBD; ++t) {
    int tok = j * CSD + t;
    float kv = 0.f, vv = 0.f;
    if (tok < NTOK) {
      long base = (((long)b * NTOK + tok) * NH + h) * DHD + lane;
      kv = k[base];
      vv = v[base];
    }
    kw[t * DHD + lane] = kv + kpe[t * DHD + lane];
    vw[t * DHD + lane] = vv + vpe[t * DHD + lane];
  }
  __syncthreads();
  float ca = 0.f, va = 0.f;
  for (int kk = 0; kk < CBD * DHD; ++kk) {
    ca += kw[kk] * Wkc[(long)kk * DHD + lane];
    va += vw[kk] * Wvc[(long)kk * DHD + lane];
  }
  long ob = (((long)b * NH + h) * NC + j) * DHD + lane;
  ck[ob] = ca;
  cv[ob] = va;
}

// ---------------- fused sparse attention per (b,h,i): compressed + topk-select + window + gates
__global__ void attn_kernel(const float* __restrict__ q, const float* __restrict__ k,
                            const float* __restrict__ v, const float* __restrict__ g,
                            const float* __restrict__ ck, const float* __restrict__ cv,
                            float* __restrict__ comb) {
  int i = blockIdx.x % NTOK;
  int h = (blockIdx.x / NTOK) % NH;
  int b = blockIdx.x / (NTOK * NH);
  int lane = threadIdx.x;  // 0..63, one wave
  __shared__ float qs[DHD];
  __shared__ float sc[NC];
  __shared__ float ss[KSELD * SBD];
  __shared__ float sw[SWD];
  __shared__ float impS[NSB];
  __shared__ int sel[KSELD];
  const float scale = 0.125f;  // 64^-0.5
  long qbase = (((long)b * NTOK + i) * NH + h) * DHD;
  qs[lane] = q[qbase + lane];
  __syncthreads();

  // ---- compressed branch ----
  long cbase = ((long)b * NH + h) * NC;
  for (int j = lane; j < NC; j += 64) {
    const float* ckp = ck + (cbase + j) * DHD;
    float s = 0.f;
    for (int d = 0; d < DHD; ++d) s += qs[d] * ckp[d];
    sc[j] = s * scale;
  }
  __syncthreads();
  float mC = -1e30f;
  for (int j = 0; j < NC; ++j) mC = fmaxf(mC, sc[j]);
  __syncthreads();
  for (int j = lane; j < NC; j += 64) sc[j] = expf(sc[j] - mC);
  __syncthreads();
  float sumC = 0.f;
  for (int j = 0; j < NC; ++j) sumC += sc[j];
  float oc = 0.f;
  for (int j = 0; j < NC; ++j) oc += sc[j] * cv[(cbase + j) * DHD + lane];
  oc /= sumC;

  // ---- importance per score-block + top-k (unnormalized exps: same ranking) ----
  if (lane < NSB) {
    float s = 0.f;
    for (int j = 0; j < NC; ++j) {
      int c = (j * CSD + CBD / 2) / SBD;
      if (c > NSB - 1) c = NSB - 1;
      if (c == lane) s += sc[j];
    }
    impS[lane] = s;
  }
  __syncthreads();
  if (lane == 0) {
    bool used[NSB];
    for (int s = 0; s < NSB; ++s) used[s] = false;
    for (int r = 0; r < KSELD; ++r) {
      int bi = 0; float bv = -1e30f;
      for (int s = 0; s < NSB; ++s)
        if (!used[s] && impS[s] > bv) { bv = impS[s]; bi = s; }
      used[bi] = true;
      sel[r] = bi;
    }
  }
  __syncthreads();

  // ---- selected-block branch (KSEL*SB = 256 tokens) ----
  for (int kk = lane; kk < KSELD * SBD; kk += 64) {
    int tok = sel[kk >> 6] * SBD + (kk & 63);
    float s;
    if (tok < NTOK) {
      const float* kp = k + (((long)b * NTOK + tok) * NH + h) * DHD;
      s = 0.f;
      for (int d = 0; d < DHD; ++d) s += qs[d] * kp[d];
      s *= scale;
    } else {
      s = -1e30f;
    }
    ss[kk] = s;
  }
  __syncthreads();
  float mS = -1e30f;
  for (int kk = 0; kk < KSELD * SBD; ++kk) mS = fmaxf(mS, ss[kk]);
  __syncthreads();
  for (int kk = lane; kk < KSELD * SBD; kk += 64) ss[kk] = expf(ss[kk] - mS);
  __syncthreads();
  float sumS = 0.f, os = 0.f;
  for (int kk = 0; kk < KSELD * SBD; ++kk) {
    float p = ss[kk];
    sumS += p;
    int tok = sel[kk >> 6] * SBD + (kk & 63);
    int tokc = tok < NTOK - 1 ? tok : NTOK - 1;
    os += p * v[(((long)b * NTOK + tokc) * NH + h) * DHD + lane];
  }
  os /= sumS;

  // ---- sliding window branch ----
  if (lane < SWD) {
    int pos = i + lane - SWD / 2;
    float s;
    if (pos >= 0 && pos < NTOK) {
      const float* kp = k + (((long)b * NTOK + pos) * NH + h) * DHD;
      s = 0.f;
      for (int d = 0; d < DHD; ++d) s += qs[d] * kp[d];
      s *= scale;
    } else {
      s = -1e30f;
    }
    sw[lane] = s;
  }
  __syncthreads();
  float mW = -1e30f;
  for (int t = 0; t < SWD; ++t) mW = fmaxf(mW, sw[t]);
  float sumW = 0.f, ow = 0.f;
  for (int t = 0; t < SWD; ++t) {
    float e = expf(sw[t] - mW);
    sumW += e;
    int pos = i + t - SWD / 2;
    int posc = pos < 0 ? 0 : (pos > NTOK - 1 ? NTOK - 1 : pos);
    ow += e * v[(((long)b * NTOK + posc) * NH + h) * DHD + lane];
  }
  ow /= sumW;

  // ---- gate combine ----
  const float* gp = g + ((long)b * NTOK + i) * (3 * NH) + h * 3;
  comb[qbase + lane] = gp[0] * oc + gp[1] * os + gp[2] * ow;
}

extern "C" void kernel_launch(void* const* d_in, const int* in_sizes, int n_in,
                              void* d_out, int out_size, void* d_ws, size_t ws_size,
                              hipStream_t stream) {
  const float* img     = (const float*)d_in[0];
  const float* patch_w = (const float*)d_in[1];
  const float* patch_b = (const float*)d_in[2];
  const float* pos_emb = (const float*)d_in[3];
  const float* cls_tok = (const float*)d_in[4];
  const float* ln1_g   = (const float*)d_in[5];
  const float* ln1_b   = (const float*)d_in[6];
  const float* Wq      = (const float*)d_in[7];
  const float* Wk      = (const float*)d_in[8];
  const float* Wv      = (const float*)d_in[9];
  const float* Wg      = (const float*)d_in[10];
  const float* Wo      = (const float*)d_in[11];
  const float* kpe     = (const float*)d_in[12];
  const float* vpe     = (const float*)d_in[13];
  const float* Wkc     = (const float*)d_in[14];
  const float* Wvc     = (const float*)d_in[15];
  const float* ln2_g   = (const float*)d_in[16];
  const float* ln2_b   = (const float*)d_in[17];
  const float* ff_w1   = (const float*)d_in[18];
  const float* ff_b1   = (const float*)d_in[19];
  const float* ff_w2   = (const float*)d_in[20];
  const float* ff_b2   = (const float*)d_in[21];
  const float* hln_g   = (const float*)d_in[22];
  const float* hln_b   = (const float*)d_in[23];
  const float* head_w  = (const float*)d_in[24];
  const float* head_b  = (const float*)d_in[25];
  float* out = (float*)d_out;

  // workspace layout (fp32), ~25 MB total
  float* ws = (float*)d_ws;
  const long XSZ = (long)BATCH * NTOK * DIMD;  // 590848
  float* x    = ws; ws += XSZ;
  float* hbuf = ws; ws += XSZ;
  float* qb   = ws; ws += XSZ;
  float* kb   = ws; ws += XSZ;
  float* vb   = ws; ws += XSZ;
  float* comb = ws; ws += XSZ;
  float* gb   = ws; ws += (long)BATCH * NTOK * 3 * NH;
  float* ckb  = ws; ws += (long)BATCH * NH * NC * DHD;
  float* cvb  = ws; ws += (long)BATCH * NH * NC * DHD;
  float* ff1  = ws; ws += (long)BATCH * NTOK * MLPD;

  const int M = BATCH * NTOK;      // 1154
  const int MT = (M + 15) / 16;    // 73
  dim3 thr16(16, 16);

  patch_kernel<<<(int)((XSZ + 255) / 256), 256, 0, stream>>>(img, patch_w, patch_b, pos_emb, cls_tok, x);

  for (int l = 0; l < 2; ++l) {
    const float* Wq_l  = Wq  + (long)l * DIMD * DIMD;
    const float* Wk_l  = Wk  + (long)l * DIMD * DIMD;
    const float* Wv_l  = Wv  + (long)l * DIMD * DIMD;
    const float* Wg_l  = Wg  + (long)l * DIMD * 3 * NH;
    const float* Wo_l  = Wo  + (long)l * DIMD * DIMD;
    const float* kpe_l = kpe + (long)l * CBD * DHD;
    const float* vpe_l = vpe + (long)l * CBD * DHD;
    const float* Wkc_l = Wkc + (long)l * CBD * DHD * DHD;
    const float* Wvc_l = Wvc + (long)l * CBD * DHD * DHD;
    const float* w1_l  = ff_w1 + (long)l * DIMD * MLPD;
    const float* b1_l  = ff_b1 + (long)l * MLPD;
    const float* w2_l  = ff_w2 + (long)l * MLPD * DIMD;
    const float* b2_l  = ff_b2 + (long)l * DIMD;

    // h = LN1(x)
    ln_kernel<<<M, 256, 0, stream>>>(x, ln1_g + (long)l * DIMD, ln1_b + (long)l * DIMD, hbuf, DIMD);
    // q,k,v = h @ W{q,k,v}
    gemm_kernel<<<dim3(DIMD / 16, MT), thr16, 0, stream>>>(hbuf, Wq_l, nullptr, nullptr, qb, M, DIMD, DIMD, 0);
    gemm_kernel<<<dim3(DIMD / 16, MT), thr16, 0, stream>>>(hbuf, Wk_l, nullptr, nullptr, kb, M, DIMD, DIMD, 0);
    gemm_kernel<<<dim3(DIMD / 16, MT), thr16, 0, stream>>>(hbuf, Wv_l, nullptr, nullptr, vb, M, DIMD, DIMD, 0);
    // g = sigmoid(h @ Wg)
    gemm_kernel<<<dim3((3 * NH + 15) / 16, MT), thr16, 0, stream>>>(hbuf, Wg_l, nullptr, nullptr, gb, M, 3 * NH, DIMD, 2);
    // compressed k/v
    ckcv_kernel<<<BATCH * NH * NC, 64, 0, stream>>>(kb, vb, kpe_l, vpe_l, Wkc_l, Wvc_l, ckb, cvb);
    // fused sparse attention -> comb (b,n,h,d)
    attn_kernel<<<BATCH * NH * NTOK, 64, 0, stream>>>(qb, kb, vb, gb, ckb, cvb, comb);
    // x = comb @ Wo + x
    gemm_kernel<<<dim3(DIMD / 16, MT), thr16, 0, stream>>>(comb, Wo_l, nullptr, x, x, M, DIMD, DIMD, 0);
    // h = LN2(x)
    ln_kernel<<<M, 256, 0, stream>>>(x, ln2_g + (long)l * DIMD, ln2_b + (long)l * DIMD, hbuf, DIMD);
    // ff1 = gelu(h @ W1 + b1)
    gemm_kernel<<<dim3(MLPD / 16, MT), thr16, 0, stream>>>(hbuf, w1_l, b1_l, nullptr, ff1, M, MLPD, DIMD, 1);
    // x = ff1 @ W2 + b2 + x
    gemm_kernel<<<dim3(DIMD / 16, MT), thr16, 0, stream>>>(ff1, w2_l, b2_l, x, x, M, DIMD, MLPD, 0);
  }

  // final: LN(x[:,0]) @ head_w + head_b
  ln_kernel<<<BATCH, 256, 0, stream>>>(x, hln_g, hln_b, hbuf, (long)NTOK * DIMD);
  gemm_kernel<<<dim3((NCLSD + 15) / 16, (BATCH + 15) / 16), thr16, 0, stream>>>(hbuf, head_w, head_b, nullptr, out, BATCH, NCLSD, DIMD, 0);
}

// Round 2
// 1499.225 us; speedup vs baseline: 1.5894x; 1.5894x over previous
//
#include <hip/hip_runtime.h>
#include <math.h>

// SparseViT forward. Round 2: bf16 MFMA GEMMs + coalesced attention.
// B=2, N=577, DIM=512, H=8, DH=64, DEPTH=2, MLP=2048, NCLS=1000
// nc=145, ns=10

#define NTOK 577
#define DIMD 512
#define NH 8
#define DHD 64
#define NC 145
#define NSB 10
#define KSELD 4
#define SBD 64
#define CBD 16
#define CSD 4
#define SWD 32
#define MLPD 2048
#define NCLSD 1000
#define BATCH 2
#define QKVN 1536   // fused q|k|v columns

typedef unsigned short ushort;
typedef __attribute__((ext_vector_type(8))) short short8;
typedef __attribute__((ext_vector_type(4))) float f32x4;

__device__ __forceinline__ ushort bf16_rne(float f) {
  union { float f; unsigned u; } v; v.f = f;
  unsigned u = v.u;
  unsigned r = (u + 0x7fffu + ((u >> 16) & 1u)) >> 16;
  return (ushort)r;
}
__device__ __forceinline__ float bf16_to_f(ushort s) {
  union { unsigned u; float f; } v; v.u = ((unsigned)s) << 16;
  return v.f;
}
__device__ __forceinline__ int imin(int a, int b) { return a < b ? a : b; }
__device__ __forceinline__ int imax(int a, int b) { return a > b ? a : b; }

// ---------------- patch embed + cls + pos ----------------
__global__ void patch_kernel(const float* __restrict__ img, const float* __restrict__ pw,
                             const float* __restrict__ pb, const float* __restrict__ pos,
                             const float* __restrict__ cls, float* __restrict__ x) {
  int idx = blockIdx.x * 256 + threadIdx.x;
  const int total = BATCH * NTOK * DIMD;
  if (idx >= total) return;
  int d = idx & (DIMD - 1);
  int i = (idx / DIMD) % NTOK;
  int b = idx / (DIMD * NTOK);
  float val;
  if (i == 0) {
    val = cls[d];
  } else {
    int p = i - 1;
    val = pb[d];
#pragma unroll
    for (int c = 0; c < 3; ++c)
      val += img[b * 3 * 576 + c * 576 + p] * pw[c * DIMD + d];
  }
  x[idx] = val + pos[i * DIMD + d];
}

// ---------------- layernorm: writes bf16 and/or fp32 ----------------
__global__ void ln_kernel(const float* __restrict__ x, const float* __restrict__ g,
                          const float* __restrict__ bb, ushort* __restrict__ out_bf,
                          float* __restrict__ out_f, long rstride) {
  int row = blockIdx.x;
  const float* xr = x + (long)row * rstride;
  int t = threadIdx.x;
  float a = xr[t], c = xr[t + 256];
  __shared__ float s1[256], s2[256];
  s1[t] = a + c;
  s2[t] = a * a + c * c;
  __syncthreads();
  for (int off = 128; off > 0; off >>= 1) {
    if (t < off) { s1[t] += s1[t + off]; s2[t] += s2[t + off]; }
    __syncthreads();
  }
  float m = s1[0] * (1.0f / 512.0f);
  float var = s2[0] * (1.0f / 512.0f) - m * m;
  float r = rsqrtf(var + 1e-5f);
  float o0 = (a - m) * r * g[t] + bb[t];
  float o1 = (c - m) * r * g[t + 256] + bb[t + 256];
  if (out_bf) {
    out_bf[(long)row * DIMD + t] = bf16_rne(o0);
    out_bf[(long)row * DIMD + t + 256] = bf16_rne(o1);
  }
  if (out_f) {
    out_f[(long)row * DIMD + t] = o0;
    out_f[(long)row * DIMD + t + 256] = o1;
  }
}

// ---------------- weight transpose + fp32->bf16: W[K][N] -> Wt[N][K] ----------------
__global__ void wtrans_kernel(const float* __restrict__ W, ushort* __restrict__ Wt,
                              int K, int N) {
  __shared__ float tile[32][33];
  int k0 = blockIdx.y * 32, n0 = blockIdx.x * 32;
  int tx = threadIdx.x, ty = threadIdx.y;  // 32 x 8
#pragma unroll
  for (int r = 0; r < 32; r += 8) tile[ty + r][tx] = W[(long)(k0 + ty + r) * N + n0 + tx];
  __syncthreads();
#pragma unroll
  for (int r = 0; r < 32; r += 8) Wt[(long)(n0 + ty + r) * K + k0 + tx] = bf16_rne(tile[tx][ty + r]);
}

// ---------------- bf16 MFMA GEMM: C = act(A @ Bt^T + bias) + resid ----------------
// A: [M][K] bf16, Bt: [N][K] bf16 (pre-transposed). K,N multiples of 64.
// act: 0 none, 1 gelu(tanh). Output to Cf (fp32) or Cbf (bf16).
__global__ __launch_bounds__(256) void mfma_gemm(
    const ushort* __restrict__ A, const ushort* __restrict__ Bt,
    const float* __restrict__ bias, const float* __restrict__ resid,
    float* __restrict__ Cf, ushort* __restrict__ Cbf,
    int M, int N, int K, int act) {
  __shared__ short As[64][72];
  __shared__ short Bs[64][72];
  int tid = threadIdx.x;
  int lane = tid & 63, wave = tid >> 6;
  int wm = wave >> 1, wn = wave & 1;
  int rowBase = blockIdx.y * 64, colBase = blockIdx.x * 64;
  int m = lane & 15, kg = lane >> 4;
  f32x4 acc[2][2] = {};
  for (int k0 = 0; k0 < K; k0 += 64) {
#pragma unroll
    for (int cc = 0; cc < 2; ++cc) {
      int c = tid * 2 + cc;
      int r = c >> 3, kc = c & 7;
      short8 av = {};
      int gr = rowBase + r;
      if (gr < M) av = *(const short8*)(A + (long)gr * K + k0 + kc * 8);
      *(short8*)&As[r][kc * 8] = av;
      short8 bv = *(const short8*)(Bt + (long)(colBase + r) * K + k0 + kc * 8);
      *(short8*)&Bs[r][kc * 8] = bv;
    }
    __syncthreads();
#pragma unroll
    for (int ks = 0; ks < 2; ++ks) {
      short8 a0 = *(const short8*)&As[wm * 32 + m][ks * 32 + kg * 8];
      short8 a1 = *(const short8*)&As[wm * 32 + 16 + m][ks * 32 + kg * 8];
      short8 b0 = *(const short8*)&Bs[wn * 32 + m][ks * 32 + kg * 8];
      short8 b1 = *(const short8*)&Bs[wn * 32 + 16 + m][ks * 32 + kg * 8];
      acc[0][0] = __builtin_amdgcn_mfma_f32_16x16x32_bf16(a0, b0, acc[0][0], 0, 0, 0);
      acc[0][1] = __builtin_amdgcn_mfma_f32_16x16x32_bf16(a0, b1, acc[0][1], 0, 0, 0);
      acc[1][0] = __builtin_amdgcn_mfma_f32_16x16x32_bf16(a1, b0, acc[1][0], 0, 0, 0);
      acc[1][1] = __builtin_amdgcn_mfma_f32_16x16x32_bf16(a1, b1, acc[1][1], 0, 0, 0);
    }
    __syncthreads();
  }
#pragma unroll
  for (int mt = 0; mt < 2; ++mt)
#pragma unroll
    for (int nt = 0; nt < 2; ++nt) {
      int col = colBase + wn * 32 + nt * 16 + (lane & 15);
#pragma unroll
      for (int r = 0; r < 4; ++r) {
        int row = rowBase + wm * 32 + mt * 16 + (lane >> 4) * 4 + r;
        if (row < M) {
          float v = acc[mt][nt][r];
          if (bias) v += bias[col];
          if (act == 1) {
            float u = 0.7978845608028654f * (v + 0.044715f * v * v * v);
            v = 0.5f * v * (1.f + tanhf(u));
          }
          if (resid) v += resid[(long)row * N + col];
          if (Cf) Cf[(long)row * N + col] = v;
          else Cbf[(long)row * N + col] = bf16_rne(v);
        }
      }
    }
}

// ---------------- small fp32 GEMM (Wg gate, head) ----------------
// a_bf16: A is bf16 if 1 else fp32. act: 0 none, 2 sigmoid.
__global__ void gemm_kernel(const void* __restrict__ A, const float* __restrict__ Bm,
                            const float* __restrict__ bias, float* __restrict__ C,
                            int M, int Nn, int K, int act, int a_bf16) {
  __shared__ float As[16][17], Bs[16][17];
  int tx = threadIdx.x, ty = threadIdx.y;
  int row = blockIdx.y * 16 + ty;
  int col = blockIdx.x * 16 + tx;
  float acc = 0.f;
  for (int k0 = 0; k0 < K; k0 += 16) {
    float av = 0.f;
    if (row < M) {
      if (a_bf16) av = bf16_to_f(((const ushort*)A)[(long)row * K + k0 + tx]);
      else av = ((const float*)A)[(long)row * K + k0 + tx];
    }
    As[ty][tx] = av;
    Bs[ty][tx] = (col < Nn) ? Bm[(long)(k0 + ty) * Nn + col] : 0.f;
    __syncthreads();
#pragma unroll
    for (int kk = 0; kk < 16; ++kk) acc += As[ty][kk] * Bs[kk][tx];
    __syncthreads();
  }
  if (row < M && col < Nn) {
    if (bias) acc += bias[col];
    if (act == 2) acc = 1.f / (1.f + expf(-acc));
    C[(long)row * Nn + col] = acc;
  }
}

// ---------------- compressed K/V from fused qkv buffer ----------------
__global__ void ckcv_kernel(const float* __restrict__ qkv,
                            const float* __restrict__ kpe, const float* __restrict__ vpe,
                            const float* __restrict__ Wkc, const float* __restrict__ Wvc,
                            float* __restrict__ ck, float* __restrict__ cv) {
  int j = blockIdx.x % NC;
  int h = (blockIdx.x / NC) % NH;
  int b = blockIdx.x / (NC * NH);
  int lane = threadIdx.x;  // 0..63
  __shared__ float kw[CBD * DHD], vw[CBD * DHD];
#pragma unroll
  for (int t = 0; t < CBD; ++t) {
    int tok = j * CSD + t;
    float kv = 0.f, vv = 0.f;
    if (tok < NTOK) {
      long base = (long)(b * NTOK + tok) * QKVN + h * DHD + lane;
      kv = qkv[base + 512];
      vv = qkv[base + 1024];
    }
    kw[t * DHD + lane] = kv + kpe[t * DHD + lane];
    vw[t * DHD + lane] = vv + vpe[t * DHD + lane];
  }
  __syncthreads();
  float ca0 = 0.f, ca1 = 0.f, va0 = 0.f, va1 = 0.f;
  for (int kk = 0; kk < CBD * DHD; kk += 2) {
    ca0 += kw[kk] * Wkc[(long)kk * DHD + lane];
    ca1 += kw[kk + 1] * Wkc[(long)(kk + 1) * DHD + lane];
    va0 += vw[kk] * Wvc[(long)kk * DHD + lane];
    va1 += vw[kk + 1] * Wvc[(long)(kk + 1) * DHD + lane];
  }
  long ob = ((long)(b * NH + h) * NC + j) * DHD + lane;
  ck[ob] = ca0 + ca1;
  cv[ob] = va0 + va1;
}

// ---------------- fused sparse attention (coalesced via LDS row staging) ----------------
__global__ void attn_kernel(const float* __restrict__ qkv, const float* __restrict__ g,
                            const float* __restrict__ ck, const float* __restrict__ cv,
                            ushort* __restrict__ comb) {
  int i = blockIdx.x % NTOK;
  int h = (blockIdx.x / NTOK) % NH;
  int b = blockIdx.x / (NTOK * NH);
  int lane = threadIdx.x;  // one wave
  __shared__ float qs[DHD];
  __shared__ float kt[64][65];
  __shared__ float sc[192];
  __shared__ float ss[256];
  __shared__ float sw[SWD];
  __shared__ float impS[NSB];
  __shared__ int sel[KSELD];
  const float scale = 0.125f;
  long rowQ = (long)(b * NTOK + i) * QKVN;
  qs[lane] = qkv[rowQ + h * DHD + lane];
  __syncthreads();

  // ---- compressed scores (3 chunks of 64 rows) ----
  long cbase = (long)(b * NH + h) * NC;
  for (int c = 0; c < 3; ++c) {
#pragma unroll 8
    for (int t = 0; t < 64; ++t) {
      int j = c * 64 + t;
      kt[t][lane] = (j < NC) ? ck[(cbase + j) * DHD + lane] : 0.f;
    }
    __syncthreads();
    int j = c * 64 + lane;
    if (j < NC) {
      float s = 0.f;
      for (int d = 0; d < DHD; ++d) s += qs[d] * kt[lane][d];
      sc[j] = s * scale;
    }
    __syncthreads();
  }
  float mC = -1e30f;
  for (int j = 0; j < NC; ++j) mC = fmaxf(mC, sc[j]);
  for (int j = lane; j < NC; j += 64) sc[j] = expf(sc[j] - mC);
  __syncthreads();
  float sumC = 0.f, oc = 0.f;
  for (int j = 0; j < NC; ++j) {
    sumC += sc[j];
    oc += sc[j] * cv[(cbase + j) * DHD + lane];
  }
  oc /= sumC;

  // ---- importance per score-block + top-k (unnormalized exps: same ranking) ----
  if (lane < NSB) {
    float s = 0.f;
    for (int j = 0; j < NC; ++j) {
      int c = (j * CSD + CBD / 2) / SBD;
      if (c > NSB - 1) c = NSB - 1;
      if (c == lane) s += sc[j];
    }
    impS[lane] = s;
  }
  __syncthreads();
  if (lane == 0) {
    bool used[NSB];
    for (int s = 0; s < NSB; ++s) used[s] = false;
    for (int r = 0; r < KSELD; ++r) {
      int bi = 0; float bv = -1e30f;
      for (int s = 0; s < NSB; ++s)
        if (!used[s] && impS[s] > bv) { bv = impS[s]; bi = s; }
      used[bi] = true;
      sel[r] = bi;
    }
  }
  __syncthreads();

  // ---- selected-block branch (4 chunks of 64 tokens) ----
  for (int c = 0; c < 4; ++c) {
    int blkTok = sel[c] * SBD;
#pragma unroll 8
    for (int t = 0; t < 64; ++t) {
      int tok = blkTok + t;
      int tokc = imin(tok, NTOK - 1);
      kt[t][lane] = qkv[(long)(b * NTOK + tokc) * QKVN + 512 + h * DHD + lane];
    }
    __syncthreads();
    int tok = blkTok + lane;
    float s;
    if (tok < NTOK) {
      float t = 0.f;
      for (int d = 0; d < DHD; ++d) t += qs[d] * kt[lane][d];
      s = t * scale;
    } else {
      s = -1e30f;
    }
    ss[c * 64 + lane] = s;
    __syncthreads();
  }
  float mS = -1e30f;
  for (int kk = 0; kk < 256; ++kk) mS = fmaxf(mS, ss[kk]);
  ss[lane]       = expf(ss[lane] - mS);
  ss[lane + 64]  = expf(ss[lane + 64] - mS);
  ss[lane + 128] = expf(ss[lane + 128] - mS);
  ss[lane + 192] = expf(ss[lane + 192] - mS);
  __syncthreads();
  float sumS = 0.f, os = 0.f;
  for (int kk = 0; kk < 256; ++kk) {
    float p = ss[kk];
    sumS += p;
    int tok = sel[kk >> 6] * SBD + (kk & 63);
    int tokc = imin(tok, NTOK - 1);
    os += p * qkv[(long)(b * NTOK + tokc) * QKVN + 1024 + h * DHD + lane];
  }
  os /= sumS;

  // ---- sliding window branch ----
#pragma unroll 8
  for (int t = 0; t < SWD; ++t) {
    int pos = i + t - SWD / 2;
    int posc = imin(imax(pos, 0), NTOK - 1);
    kt[t][lane] = qkv[(long)(b * NTOK + posc) * QKVN + 512 + h * DHD + lane];
  }
  __syncthreads();
  if (lane < SWD) {
    int pos = i + lane - SWD / 2;
    float s;
    if (pos >= 0 && pos < NTOK) {
      float t = 0.f;
      for (int d = 0; d < DHD; ++d) t += qs[d] * kt[lane][d];
      s = t * scale;
    } else {
      s = -1e30f;
    }
    sw[lane] = s;
  }
  __syncthreads();
  float mW = -1e30f;
  for (int t = 0; t < SWD; ++t) mW = fmaxf(mW, sw[t]);
  float sumW = 0.f, ow = 0.f;
  for (int t = 0; t < SWD; ++t) {
    float e = expf(sw[t] - mW);
    sumW += e;
    int pos = i + t - SWD / 2;
    int posc = imin(imax(pos, 0), NTOK - 1);
    ow += e * qkv[(long)(b * NTOK + posc) * QKVN + 1024 + h * DHD + lane];
  }
  ow /= sumW;

  const float* gp = g + (long)(b * NTOK + i) * (3 * NH) + h * 3;
  float val = gp[0] * oc + gp[1] * os + gp[2] * ow;
  comb[(long)(b * NTOK + i) * DIMD + h * DHD + lane] = bf16_rne(val);
}

extern "C" void kernel_launch(void* const* d_in, const int* in_sizes, int n_in,
                              void* d_out, int out_size, void* d_ws, size_t ws_size,
                              hipStream_t stream) {
  const float* img     = (const float*)d_in[0];
  const float* patch_w = (const float*)d_in[1];
  const float* patch_b = (const float*)d_in[2];
  const float* pos_emb = (const float*)d_in[3];
  const float* cls_tok = (const float*)d_in[4];
  const float* ln1_g   = (const float*)d_in[5];
  const float* ln1_b   = (const float*)d_in[6];
  const float* Wq      = (const float*)d_in[7];
  const float* Wk      = (const float*)d_in[8];
  const float* Wv      = (const float*)d_in[9];
  const float* Wg      = (const float*)d_in[10];
  const float* Wo      = (const float*)d_in[11];
  const float* kpe     = (const float*)d_in[12];
  const float* vpe     = (const float*)d_in[13];
  const float* Wkc     = (const float*)d_in[14];
  const float* Wvc     = (const float*)d_in[15];
  const float* ln2_g   = (const float*)d_in[16];
  const float* ln2_b   = (const float*)d_in[17];
  const float* ff_w1   = (const float*)d_in[18];
  const float* ff_b1   = (const float*)d_in[19];
  const float* ff_w2   = (const float*)d_in[20];
  const float* ff_b2   = (const float*)d_in[21];
  const float* hln_g   = (const float*)d_in[22];
  const float* hln_b   = (const float*)d_in[23];
  const float* head_w  = (const float*)d_in[24];
  const float* head_b  = (const float*)d_in[25];
  float* out = (float*)d_out;

  // ---- workspace carve (all 16B-aligned sizes), ~24.2 MB ----
  char* p = (char*)d_ws;
  const long MROW = (long)BATCH * NTOK;            // 1154
  float* x       = (float*)p;  p += MROW * DIMD * 4;          // 2.36 MB
  float* qkv     = (float*)p;  p += MROW * QKVN * 4;          // 7.09 MB
  ushort* h_bf   = (ushort*)p; p += MROW * DIMD * 2;          // 1.18 MB
  ushort* comb_bf= (ushort*)p; p += MROW * DIMD * 2;          // 1.18 MB
  ushort* ff1_bf = (ushort*)p; p += MROW * MLPD * 2;          // 4.73 MB
  float* gb      = (float*)p;  p += MROW * 3 * NH * 4;        // 0.11 MB
  float* ckb     = (float*)p;  p += (long)BATCH * NH * NC * DHD * 4;
  float* cvb     = (float*)p;  p += (long)BATCH * NH * NC * DHD * 4;
  float* hfin    = (float*)p;  p += BATCH * DIMD * 4;
  ushort* wqkv_t = (ushort*)p; p += (long)QKVN * DIMD * 2;    // 1.57 MB
  ushort* wo_t   = (ushort*)p; p += (long)DIMD * DIMD * 2;    // 0.52 MB
  ushort* w1_t   = (ushort*)p; p += (long)MLPD * DIMD * 2;    // 2.10 MB
  ushort* w2_t   = (ushort*)p; p += (long)DIMD * MLPD * 2;    // 2.10 MB

  const int M = (int)MROW;                  // 1154
  const int MB64 = (M + 63) / 64;           // 19
  dim3 thr16(16, 16), thrT(32, 8);

  patch_kernel<<<(M * DIMD + 255) / 256, 256, 0, stream>>>(img, patch_w, patch_b, pos_emb, cls_tok, x);

  for (int l = 0; l < 2; ++l) {
    const float* Wq_l  = Wq + (long)l * DIMD * DIMD;
    const float* Wk_l  = Wk + (long)l * DIMD * DIMD;
    const float* Wv_l  = Wv + (long)l * DIMD * DIMD;
    const float* Wg_l  = Wg + (long)l * DIMD * 3 * NH;
    const float* Wo_l  = Wo + (long)l * DIMD * DIMD;
    const float* kpe_l = kpe + (long)l * CBD * DHD;
    const float* vpe_l = vpe + (long)l * CBD * DHD;
    const float* Wkc_l = Wkc + (long)l * CBD * DHD * DHD;
    const float* Wvc_l = Wvc + (long)l * CBD * DHD * DHD;
    const float* w1_l  = ff_w1 + (long)l * DIMD * MLPD;
    const float* b1_l  = ff_b1 + (long)l * MLPD;
    const float* w2_l  = ff_w2 + (long)l * MLPD * DIMD;
    const float* b2_l  = ff_b2 + (long)l * DIMD;

    // weight transposes -> bf16 (stream-ordered, reused buffers)
    wtrans_kernel<<<dim3(16, 16), thrT, 0, stream>>>(Wq_l, wqkv_t, DIMD, DIMD);
    wtrans_kernel<<<dim3(16, 16), thrT, 0, stream>>>(Wk_l, wqkv_t + 512 * DIMD, DIMD, DIMD);
    wtrans_kernel<<<dim3(16, 16), thrT, 0, stream>>>(Wv_l, wqkv_t + 1024 * DIMD, DIMD, DIMD);
    wtrans_kernel<<<dim3(16, 16), thrT, 0, stream>>>(Wo_l, wo_t, DIMD, DIMD);
    wtrans_kernel<<<dim3(64, 16), thrT, 0, stream>>>(w1_l, w1_t, DIMD, MLPD);
    wtrans_kernel<<<dim3(16, 64), thrT, 0, stream>>>(w2_l, w2_t, MLPD, DIMD);

    // h = LN1(x) -> bf16
    ln_kernel<<<M, 256, 0, stream>>>(x, ln1_g + (long)l * DIMD, ln1_b + (long)l * DIMD, h_bf, nullptr, DIMD);
    // qkv = h @ [Wq|Wk|Wv]
    mfma_gemm<<<dim3(QKVN / 64, MB64), 256, 0, stream>>>(h_bf, wqkv_t, nullptr, nullptr, qkv, nullptr, M, QKVN, DIMD, 0);
    // gates
    gemm_kernel<<<dim3(2, (M + 15) / 16), thr16, 0, stream>>>(h_bf, Wg_l, nullptr, gb, M, 3 * NH, DIMD, 2, 1);
    // compressed k/v
    ckcv_kernel<<<BATCH * NH * NC, 64, 0, stream>>>(qkv, kpe_l, vpe_l, Wkc_l, Wvc_l, ckb, cvb);
    // fused sparse attention -> comb bf16
    attn_kernel<<<BATCH * NH * NTOK, 64, 0, stream>>>(qkv, gb, ckb, cvb, comb_bf);
    // x = comb @ Wo + x
    mfma_gemm<<<dim3(DIMD / 64, MB64), 256, 0, stream>>>(comb_bf, wo_t, nullptr, x, x, nullptr, M, DIMD, DIMD, 0);
    // h = LN2(x) -> bf16
    ln_kernel<<<M, 256, 0, stream>>>(x, ln2_g + (long)l * DIMD, ln2_b + (long)l * DIMD, h_bf, nullptr, DIMD);
    // ff1 = gelu(h @ W1 + b1) -> bf16
    mfma_gemm<<<dim3(MLPD / 64, MB64), 256, 0, stream>>>(h_bf, w1_t, b1_l, nullptr, nullptr, ff1_bf, M, MLPD, DIMD, 1);
    // x = ff1 @ W2 + b2 + x
    mfma_gemm<<<dim3(DIMD / 64, MB64), 256, 0, stream>>>(ff1_bf, w2_t, b2_l, x, x, nullptr, M, DIMD, MLPD, 0);
  }

  // final: LN(x[:,0]) fp32 -> head
  ln_kernel<<<BATCH, 256, 0, stream>>>(x, hln_g, hln_b, nullptr, hfin, (long)NTOK * DIMD);
  gemm_kernel<<<dim3((NCLSD + 15) / 16, 1), thr16, 0, stream>>>(hfin, head_w, head_b, out, BATCH, NCLSD, DIMD, 0, 0);
}

// Round 3
// 877.434 us; speedup vs baseline: 2.7158x; 1.7086x over previous
//
#include <hip/hip_runtime.h>
#include <math.h>

// SparseViT forward. Round 3: high-occupancy attention (4 queries/block, float4
// row dots, shuffle reductions) + ck/cv via MFMA GEMM + gate via MFMA.
// B=2, N=577, DIM=512, H=8, DH=64, DEPTH=2, MLP=2048, NCLS=1000, nc=145, ns=10

#define NTOK 577
#define DIMD 512
#define NH 8
#define DHD 64
#define NC 145
#define NSB 10
#define KSELD 4
#define SBD 64
#define CBD 16
#define CSD 4
#define SWD 32
#define MLPD 2048
#define NCLSD 1000
#define BATCH 2
#define QKVN 1536   // fused q|k|v columns

typedef unsigned short ushort;
typedef __attribute__((ext_vector_type(8))) short short8;
typedef __attribute__((ext_vector_type(4))) short short4v;
typedef __attribute__((ext_vector_type(4))) float f32x4;

__device__ __forceinline__ ushort bf16_rne(float f) {
  union { float f; unsigned u; } v; v.f = f;
  unsigned u = v.u;
  unsigned r = (u + 0x7fffu + ((u >> 16) & 1u)) >> 16;
  return (ushort)r;
}
__device__ __forceinline__ float bf16_to_f(ushort s) {
  union { unsigned u; float f; } v; v.u = ((unsigned)s) << 16;
  return v.f;
}
__device__ __forceinline__ int imin(int a, int b) { return a < b ? a : b; }
__device__ __forceinline__ int imax(int a, int b) { return a > b ? a : b; }

// ---------------- patch embed + cls + pos ----------------
__global__ void patch_kernel(const float* __restrict__ img, const float* __restrict__ pw,
                             const float* __restrict__ pb, const float* __restrict__ pos,
                             const float* __restrict__ cls, float* __restrict__ x) {
  int idx = blockIdx.x * 256 + threadIdx.x;
  const int total = BATCH * NTOK * DIMD;
  if (idx >= total) return;
  int d = idx & (DIMD - 1);
  int i = (idx / DIMD) % NTOK;
  int b = idx / (DIMD * NTOK);
  float val;
  if (i == 0) {
    val = cls[d];
  } else {
    int p = i - 1;
    val = pb[d];
#pragma unroll
    for (int c = 0; c < 3; ++c)
      val += img[b * 3 * 576 + c * 576 + p] * pw[c * DIMD + d];
  }
  x[idx] = val + pos[i * DIMD + d];
}

// ---------------- layernorm: writes bf16 and/or fp32 ----------------
__global__ void ln_kernel(const float* __restrict__ x, const float* __restrict__ g,
                          const float* __restrict__ bb, ushort* __restrict__ out_bf,
                          float* __restrict__ out_f, long rstride) {
  int row = blockIdx.x;
  const float* xr = x + (long)row * rstride;
  int t = threadIdx.x;
  float a = xr[t], c = xr[t + 256];
  __shared__ float s1[256], s2[256];
  s1[t] = a + c;
  s2[t] = a * a + c * c;
  __syncthreads();
  for (int off = 128; off > 0; off >>= 1) {
    if (t < off) { s1[t] += s1[t + off]; s2[t] += s2[t + off]; }
    __syncthreads();
  }
  float m = s1[0] * (1.0f / 512.0f);
  float var = s2[0] * (1.0f / 512.0f) - m * m;
  float r = rsqrtf(var + 1e-5f);
  float o0 = (a - m) * r * g[t] + bb[t];
  float o1 = (c - m) * r * g[t + 256] + bb[t + 256];
  if (out_bf) {
    out_bf[(long)row * DIMD + t] = bf16_rne(o0);
    out_bf[(long)row * DIMD + t + 256] = bf16_rne(o1);
  }
  if (out_f) {
    out_f[(long)row * DIMD + t] = o0;
    out_f[(long)row * DIMD + t + 256] = o1;
  }
}

// ---------------- weight transpose + fp32->bf16: W[K][N] -> Wt[Npad][K] ----------------
__global__ void wtrans_kernel(const float* __restrict__ W, ushort* __restrict__ Wt,
                              int K, int N) {
  __shared__ float tile[32][33];
  int k0 = blockIdx.y * 32, n0 = blockIdx.x * 32;
  int tx = threadIdx.x, ty = threadIdx.y;  // 32 x 8
#pragma unroll
  for (int r = 0; r < 32; r += 8)
    tile[ty + r][tx] = (n0 + tx < N) ? W[(long)(k0 + ty + r) * N + n0 + tx] : 0.f;
  __syncthreads();
#pragma unroll
  for (int r = 0; r < 32; r += 8) Wt[(long)(n0 + ty + r) * K + k0 + tx] = bf16_rne(tile[tx][ty + r]);
}

// ---------------- bf16 MFMA GEMM: C = act(A @ Bt^T + bias) + resid ----------------
// A: [M][K] bf16, Bt: [N][K] bf16 (pre-transposed). K,N multiples of 64.
// act: 0 none, 1 gelu(tanh), 2 sigmoid. Output to Cf (fp32) or Cbf (bf16).
__global__ __launch_bounds__(256) void mfma_gemm(
    const ushort* __restrict__ A, const ushort* __restrict__ Bt,
    const float* __restrict__ bias, const float* __restrict__ resid,
    float* __restrict__ Cf, ushort* __restrict__ Cbf,
    int M, int N, int K, int act) {
  __shared__ short As[64][72];
  __shared__ short Bs[64][72];
  int tid = threadIdx.x;
  int lane = tid & 63, wave = tid >> 6;
  int wm = wave >> 1, wn = wave & 1;
  int rowBase = blockIdx.y * 64, colBase = blockIdx.x * 64;
  int m = lane & 15, kg = lane >> 4;
  f32x4 acc[2][2] = {};
  for (int k0 = 0; k0 < K; k0 += 64) {
#pragma unroll
    for (int cc = 0; cc < 2; ++cc) {
      int c = tid * 2 + cc;
      int r = c >> 3, kc = c & 7;
      short8 av = {};
      int gr = rowBase + r;
      if (gr < M) av = *(const short8*)(A + (long)gr * K + k0 + kc * 8);
      *(short8*)&As[r][kc * 8] = av;
      short8 bv = *(const short8*)(Bt + (long)(colBase + r) * K + k0 + kc * 8);
      *(short8*)&Bs[r][kc * 8] = bv;
    }
    __syncthreads();
#pragma unroll
    for (int ks = 0; ks < 2; ++ks) {
      short8 a0 = *(const short8*)&As[wm * 32 + m][ks * 32 + kg * 8];
      short8 a1 = *(const short8*)&As[wm * 32 + 16 + m][ks * 32 + kg * 8];
      short8 b0 = *(const short8*)&Bs[wn * 32 + m][ks * 32 + kg * 8];
      short8 b1 = *(const short8*)&Bs[wn * 32 + 16 + m][ks * 32 + kg * 8];
      acc[0][0] = __builtin_amdgcn_mfma_f32_16x16x32_bf16(a0, b0, acc[0][0], 0, 0, 0);
      acc[0][1] = __builtin_amdgcn_mfma_f32_16x16x32_bf16(a0, b1, acc[0][1], 0, 0, 0);
      acc[1][0] = __builtin_amdgcn_mfma_f32_16x16x32_bf16(a1, b0, acc[1][0], 0, 0, 0);
      acc[1][1] = __builtin_amdgcn_mfma_f32_16x16x32_bf16(a1, b1, acc[1][1], 0, 0, 0);
    }
    __syncthreads();
  }
#pragma unroll
  for (int mt = 0; mt < 2; ++mt)
#pragma unroll
    for (int nt = 0; nt < 2; ++nt) {
      int col = colBase + wn * 32 + nt * 16 + (lane & 15);
#pragma unroll
      for (int r = 0; r < 4; ++r) {
        int row = rowBase + wm * 32 + mt * 16 + (lane >> 4) * 4 + r;
        if (row < M) {
          float v = acc[mt][nt][r];
          if (bias) v += bias[col];
          if (act == 1) {
            float u = 0.7978845608028654f * (v + 0.044715f * v * v * v);
            v = 0.5f * v * (1.f + tanhf(u));
          } else if (act == 2) {
            v = 1.f / (1.f + __expf(-v));
          }
          if (resid) v += resid[(long)row * N + col];
          if (Cf) Cf[(long)row * N + col] = v;
          else Cbf[(long)row * N + col] = bf16_rne(v);
        }
      }
    }
}

// ---------------- small fp32 GEMM (head only) ----------------
__global__ void gemm_kernel(const float* __restrict__ A, const float* __restrict__ Bm,
                            const float* __restrict__ bias, float* __restrict__ C,
                            int M, int Nn, int K) {
  __shared__ float As[16][17], Bs[16][17];
  int tx = threadIdx.x, ty = threadIdx.y;
  int row = blockIdx.y * 16 + ty;
  int col = blockIdx.x * 16 + tx;
  float acc = 0.f;
  for (int k0 = 0; k0 < K; k0 += 16) {
    As[ty][tx] = (row < M) ? A[(long)row * K + k0 + tx] : 0.f;
    Bs[ty][tx] = (col < Nn) ? Bm[(long)(k0 + ty) * Nn + col] : 0.f;
    __syncthreads();
#pragma unroll
    for (int kk = 0; kk < 16; ++kk) acc += As[ty][kk] * Bs[kk][tx];
    __syncthreads();
  }
  if (row < M && col < Nn) {
    if (bias) acc += bias[col];
    C[(long)row * Nn + col] = acc;
  }
}

// ---------------- kw/vw build: row r=(b,h,j), cols t*64+d (bf16) ----------------
__global__ void kwbuild_kernel(const float* __restrict__ qkv,
                               const float* __restrict__ kpe, const float* __restrict__ vpe,
                               ushort* __restrict__ kwm, ushort* __restrict__ vwm) {
  int r = blockIdx.x;               // 0..2319
  int j = r % NC;
  int bh = r / NC;
  int h = bh & 7, b = bh >> 3;
  int t = threadIdx.x >> 4;         // 0..15 window slot
  int d4 = threadIdx.x & 15;        // float4 index within DH
  int tok = j * CSD + t;
  float4 kv = {0.f, 0.f, 0.f, 0.f}, vv = kv;
  if (tok < NTOK) {
    long base = (long)(b * NTOK + tok) * QKVN + h * DHD + d4 * 4;
    kv = *(const float4*)(qkv + base + 512);
    vv = *(const float4*)(qkv + base + 1024);
  }
  float4 kp = *(const float4*)(kpe + t * DHD + d4 * 4);
  float4 vp = *(const float4*)(vpe + t * DHD + d4 * 4);
  short4v ko, vo;
  ko.x = (short)bf16_rne(kv.x + kp.x); ko.y = (short)bf16_rne(kv.y + kp.y);
  ko.z = (short)bf16_rne(kv.z + kp.z); ko.w = (short)bf16_rne(kv.w + kp.w);
  vo.x = (short)bf16_rne(vv.x + vp.x); vo.y = (short)bf16_rne(vv.y + vp.y);
  vo.z = (short)bf16_rne(vv.z + vp.z); vo.w = (short)bf16_rne(vv.w + vp.w);
  long ob = (long)r * 1024 + t * DHD + d4 * 4;
  *(short4v*)(kwm + ob) = ko;
  *(short4v*)(vwm + ob) = vo;
}

// ---------------- fused sparse attention: 4 queries/block (one per wave) ----------------
__global__ __launch_bounds__(256, 4) void attn_kernel(
    const float* __restrict__ qkv, const float* __restrict__ g,
    const float* __restrict__ ck, const float* __restrict__ cv,
    ushort* __restrict__ comb) {
  int qt = blockIdx.x % NC;          // 145 tiles of 4 queries (577 -> last partial)
  int bh = blockIdx.x / NC;
  int h = bh & 7, b = bh >> 3;
  int tid = threadIdx.x, lane = tid & 63, w = tid >> 6;
  int i0 = qt * 4 + w;
  int i = imin(i0, NTOK - 1);
  bool valid = (i0 < NTOK);

  __shared__ float qsL[4][64];
  __shared__ float scL[4][192];
  __shared__ float ssL[4][256];
  __shared__ float swL[4][32];
  __shared__ float impL[4][NSB];
  __shared__ int selL[4][KSELD];
  float* qs = qsL[w]; float* sc = scL[w]; float* ss = ssL[w];
  float* swv = swL[w]; float* imp = impL[w]; int* sel = selL[w];

  const float scale = 0.125f;
  const long rowStride = QKVN;
  long rowQ = (long)(b * NTOK + i) * rowStride + h * DHD;
  qs[lane] = qkv[rowQ + lane];
  __syncthreads();
  const float4* qs4 = (const float4*)qs;

  long cbase = (long)(b * NH + h) * NC;

  // ---- compressed scores (lane = key, 3 chunks) ----
  float e[3], mC = -1e30f;
#pragma unroll
  for (int c = 0; c < 3; ++c) {
    int j = c * 64 + lane;
    int jc = imin(j, NC - 1);
    const float4* kr = (const float4*)(ck + (cbase + jc) * DHD);
    float s = 0.f;
#pragma unroll
    for (int d = 0; d < 16; ++d) {
      float4 kv = kr[d], qv = qs4[d];
      s += kv.x * qv.x + kv.y * qv.y + kv.z * qv.z + kv.w * qv.w;
    }
    s = (j < NC) ? s * scale : -1e30f;
    e[c] = s;
    mC = fmaxf(mC, s);
  }
#pragma unroll
  for (int msk = 1; msk < 64; msk <<= 1) mC = fmaxf(mC, __shfl_xor(mC, msk, 64));
  float sumC = 0.f;
#pragma unroll
  for (int c = 0; c < 3; ++c) {
    float ev = (e[c] > -1e29f) ? __expf(e[c] - mC) : 0.f;
    sc[c * 64 + lane] = ev;
    sumC += ev;
  }
#pragma unroll
  for (int msk = 1; msk < 64; msk <<= 1) sumC += __shfl_xor(sumC, msk, 64);
  __syncthreads();

  // ---- out_c (lane = d) ----
  float oc = 0.f;
#pragma unroll 4
  for (int j = 0; j < NC; ++j) oc += sc[j] * cv[(cbase + j) * DHD + lane];
  oc /= sumC;

  // ---- importance + top-k ----
  // centers(j) = (4j+8)/64 == s  <=>  j in [16s-2, 16s+13]
  if (lane < NSB) {
    int lo = imax(0, 16 * lane - 2), hi = imin(NC - 1, 16 * lane + 13);
    float s = 0.f;
    for (int j = lo; j <= hi; ++j) s += sc[j];
    imp[lane] = s;
  }
  __syncthreads();
  if (lane == 0) {
    unsigned used = 0;
    for (int r = 0; r < KSELD; ++r) {
      int bi = 0; float bv = -1e30f;
      for (int s = 0; s < NSB; ++s)
        if (!((used >> s) & 1u) && imp[s] > bv) { bv = imp[s]; bi = s; }
      used |= 1u << bi;
      sel[r] = bi;
    }
  }
  __syncthreads();

  // ---- selected blocks (lane = token within chunk) ----
  long kbase = (long)b * NTOK * rowStride + 512 + h * DHD;
  long vbase = (long)b * NTOK * rowStride + 1024 + h * DHD;
  float es[4], mS = -1e30f;
#pragma unroll
  for (int c = 0; c < 4; ++c) {
    int tok = sel[c] * SBD + lane;
    int tokc = imin(tok, NTOK - 1);
    const float4* kr = (const float4*)(qkv + kbase + (long)tokc * rowStride);
    float s = 0.f;
#pragma unroll
    for (int d = 0; d < 16; ++d) {
      float4 kv = kr[d], qv = qs4[d];
      s += kv.x * qv.x + kv.y * qv.y + kv.z * qv.z + kv.w * qv.w;
    }
    s = (tok < NTOK) ? s * scale : -1e30f;
    es[c] = s;
    mS = fmaxf(mS, s);
  }
#pragma unroll
  for (int msk = 1; msk < 64; msk <<= 1) mS = fmaxf(mS, __shfl_xor(mS, msk, 64));
  float sumS = 0.f;
#pragma unroll
  for (int c = 0; c < 4; ++c) {
    float ev = (es[c] > -1e29f) ? __expf(es[c] - mS) : 0.f;
    ss[c * 64 + lane] = ev;
    sumS += ev;
  }
#pragma unroll
  for (int msk = 1; msk < 64; msk <<= 1) sumS += __shfl_xor(sumS, msk, 64);
  __syncthreads();

  // ---- out_s (lane = d) ----
  float os = 0.f;
#pragma unroll 8
  for (int kk = 0; kk < KSELD * SBD; ++kk) {
    int tok = sel[kk >> 6] * SBD + (kk & 63);
    int tokc = imin(tok, NTOK - 1);
    os += ss[kk] * qkv[vbase + (long)tokc * rowStride + lane];
  }
  os /= sumS;

  // ---- sliding window (both 32-halves duplicate the work -> butterfly over 32) ----
  float sw_s;
  {
    int pos = i + (lane & 31) - SWD / 2;
    int posc = imin(imax(pos, 0), NTOK - 1);
    const float4* kr = (const float4*)(qkv + kbase + (long)posc * rowStride);
    float s = 0.f;
#pragma unroll
    for (int d = 0; d < 16; ++d) {
      float4 kv = kr[d], qv = qs4[d];
      s += kv.x * qv.x + kv.y * qv.y + kv.z * qv.z + kv.w * qv.w;
    }
    sw_s = (pos >= 0 && pos < NTOK) ? s * scale : -1e30f;
  }
  float mW = sw_s;
#pragma unroll
  for (int msk = 1; msk < 32; msk <<= 1) mW = fmaxf(mW, __shfl_xor(mW, msk, 64));
  float ew = (sw_s > -1e29f) ? __expf(sw_s - mW) : 0.f;
  float sumW = ew;
#pragma unroll
  for (int msk = 1; msk < 32; msk <<= 1) sumW += __shfl_xor(sumW, msk, 64);
  if (lane < SWD) swv[lane] = ew;
  __syncthreads();

  // ---- out_w (lane = d) ----
  float ow = 0.f;
#pragma unroll 4
  for (int t = 0; t < SWD; ++t) {
    int pos = i + t - SWD / 2;
    int posc = imin(imax(pos, 0), NTOK - 1);
    ow += swv[t] * qkv[vbase + (long)posc * rowStride + lane];
  }
  ow /= sumW;

  // ---- gate combine + store bf16 ----
  const float* gp = g + (long)(b * NTOK + i) * 64 + h * 3;
  float val = gp[0] * oc + gp[1] * os + gp[2] * ow;
  if (valid) comb[(long)(b * NTOK + i) * DIMD + h * DHD + lane] = bf16_rne(val);
}

extern "C" void kernel_launch(void* const* d_in, const int* in_sizes, int n_in,
                              void* d_out, int out_size, void* d_ws, size_t ws_size,
                              hipStream_t stream) {
  const float* img     = (const float*)d_in[0];
  const float* patch_w = (const float*)d_in[1];
  const float* patch_b = (const float*)d_in[2];
  const float* pos_emb = (const float*)d_in[3];
  const float* cls_tok = (const float*)d_in[4];
  const float* ln1_g   = (const float*)d_in[5];
  const float* ln1_b   = (const float*)d_in[6];
  const float* Wq      = (const float*)d_in[7];
  const float* Wk      = (const float*)d_in[8];
  const float* Wv      = (const float*)d_in[9];
  const float* Wg      = (const float*)d_in[10];
  const float* Wo      = (const float*)d_in[11];
  const float* kpe     = (const float*)d_in[12];
  const float* vpe     = (const float*)d_in[13];
  const float* Wkc     = (const float*)d_in[14];
  const float* Wvc     = (const float*)d_in[15];
  const float* ln2_g   = (const float*)d_in[16];
  const float* ln2_b   = (const float*)d_in[17];
  const float* ff_w1   = (const float*)d_in[18];
  const float* ff_b1   = (const float*)d_in[19];
  const float* ff_w2   = (const float*)d_in[20];
  const float* ff_b2   = (const float*)d_in[21];
  const float* hln_g   = (const float*)d_in[22];
  const float* hln_b   = (const float*)d_in[23];
  const float* head_w  = (const float*)d_in[24];
  const float* head_b  = (const float*)d_in[25];
  float* out = (float*)d_out;

  // ---- workspace carve (~34 MB) ----
  char* p = (char*)d_ws;
  const long MROW = (long)BATCH * NTOK;            // 1154
  float* x       = (float*)p;  p += MROW * DIMD * 4;
  float* qkv     = (float*)p;  p += MROW * QKVN * 4;
  ushort* h_bf   = (ushort*)p; p += MROW * DIMD * 2;
  ushort* comb_bf= (ushort*)p; p += MROW * DIMD * 2;
  ushort* ff1_bf = (ushort*)p; p += MROW * MLPD * 2;
  float* gb      = (float*)p;  p += MROW * 64 * 4;
  float* ckb     = (float*)p;  p += (long)BATCH * NH * NC * DHD * 4;
  float* cvb     = (float*)p;  p += (long)BATCH * NH * NC * DHD * 4;
  float* hfin    = (float*)p;  p += BATCH * DIMD * 4;
  ushort* wqkv_t = (ushort*)p; p += (long)QKVN * DIMD * 2;
  ushort* wo_t   = (ushort*)p; p += (long)DIMD * DIMD * 2;
  ushort* w1_t   = (ushort*)p; p += (long)MLPD * DIMD * 2;
  ushort* w2_t   = (ushort*)p; p += (long)DIMD * MLPD * 2;
  ushort* wg_t   = (ushort*)p; p += (long)64 * DIMD * 2;
  ushort* wkc_t  = (ushort*)p; p += (long)64 * 1024 * 2;
  ushort* wvc_t  = (ushort*)p; p += (long)64 * 1024 * 2;
  ushort* kwm    = (ushort*)p; p += (long)BATCH * NH * NC * 1024 * 2;
  ushort* vwm    = (ushort*)p; p += (long)BATCH * NH * NC * 1024 * 2;

  const int M = (int)MROW;                  // 1154
  const int MB64 = (M + 63) / 64;           // 19
  const int MCK = BATCH * NH * NC;          // 2320
  dim3 thr16(16, 16), thrT(32, 8);

  patch_kernel<<<(M * DIMD + 255) / 256, 256, 0, stream>>>(img, patch_w, patch_b, pos_emb, cls_tok, x);

  for (int l = 0; l < 2; ++l) {
    const float* Wq_l  = Wq + (long)l * DIMD * DIMD;
    const float* Wk_l  = Wk + (long)l * DIMD * DIMD;
    const float* Wv_l  = Wv + (long)l * DIMD * DIMD;
    const float* Wg_l  = Wg + (long)l * DIMD * 3 * NH;
    const float* Wo_l  = Wo + (long)l * DIMD * DIMD;
    const float* kpe_l = kpe + (long)l * CBD * DHD;
    const float* vpe_l = vpe + (long)l * CBD * DHD;
    const float* Wkc_l = Wkc + (long)l * CBD * DHD * DHD;
    const float* Wvc_l = Wvc + (long)l * CBD * DHD * DHD;
    const float* w1_l  = ff_w1 + (long)l * DIMD * MLPD;
    const float* b1_l  = ff_b1 + (long)l * MLPD;
    const float* w2_l  = ff_w2 + (long)l * MLPD * DIMD;
    const float* b2_l  = ff_b2 + (long)l * DIMD;

    // weight transposes -> bf16
    wtrans_kernel<<<dim3(16, 16), thrT, 0, stream>>>(Wq_l, wqkv_t, DIMD, DIMD);
    wtrans_kernel<<<dim3(16, 16), thrT, 0, stream>>>(Wk_l, wqkv_t + 512 * DIMD, DIMD, DIMD);
    wtrans_kernel<<<dim3(16, 16), thrT, 0, stream>>>(Wv_l, wqkv_t + 1024 * DIMD, DIMD, DIMD);
    wtrans_kernel<<<dim3(16, 16), thrT, 0, stream>>>(Wo_l, wo_t, DIMD, DIMD);
    wtrans_kernel<<<dim3(64, 16), thrT, 0, stream>>>(w1_l, w1_t, DIMD, MLPD);
    wtrans_kernel<<<dim3(16, 64), thrT, 0, stream>>>(w2_l, w2_t, MLPD, DIMD);
    wtrans_kernel<<<dim3(2, 16), thrT, 0, stream>>>(Wg_l, wg_t, DIMD, 3 * NH);
    wtrans_kernel<<<dim3(2, 32), thrT, 0, stream>>>(Wkc_l, wkc_t, 1024, DHD);
    wtrans_kernel<<<dim3(2, 32), thrT, 0, stream>>>(Wvc_l, wvc_t, 1024, DHD);

    // h = LN1(x) -> bf16
    ln_kernel<<<M, 256, 0, stream>>>(x, ln1_g + (long)l * DIMD, ln1_b + (long)l * DIMD, h_bf, nullptr, DIMD);
    // qkv = h @ [Wq|Wk|Wv]
    mfma_gemm<<<dim3(QKVN / 64, MB64), 256, 0, stream>>>(h_bf, wqkv_t, nullptr, nullptr, qkv, nullptr, M, QKVN, DIMD, 0);
    // gates: sigmoid(h @ Wg) padded to 64 cols
    mfma_gemm<<<dim3(1, MB64), 256, 0, stream>>>(h_bf, wg_t, nullptr, nullptr, gb, nullptr, M, 64, DIMD, 2);
    // kw/vw matrices (bf16) then ck/cv GEMMs
    kwbuild_kernel<<<MCK, 256, 0, stream>>>(qkv, kpe_l, vpe_l, kwm, vwm);
    mfma_gemm<<<dim3(1, (MCK + 63) / 64), 256, 0, stream>>>(kwm, wkc_t, nullptr, nullptr, ckb, nullptr, MCK, 64, 1024, 0);
    mfma_gemm<<<dim3(1, (MCK + 63) / 64), 256, 0, stream>>>(vwm, wvc_t, nullptr, nullptr, cvb, nullptr, MCK, 64, 1024, 0);
    // fused sparse attention -> comb bf16
    attn_kernel<<<BATCH * NH * NC, 256, 0, stream>>>(qkv, gb, ckb, cvb, comb_bf);
    // x = comb @ Wo + x
    mfma_gemm<<<dim3(DIMD / 64, MB64), 256, 0, stream>>>(comb_bf, wo_t, nullptr, x, x, nullptr, M, DIMD, DIMD, 0);
    // h = LN2(x) -> bf16
    ln_kernel<<<M, 256, 0, stream>>>(x, ln2_g + (long)l * DIMD, ln2_b + (long)l * DIMD, h_bf, nullptr, DIMD);
    // ff1 = gelu(h @ W1 + b1) -> bf16
    mfma_gemm<<<dim3(MLPD / 64, MB64), 256, 0, stream>>>(h_bf, w1_t, b1_l, nullptr, nullptr, ff1_bf, M, MLPD, DIMD, 1);
    // x = ff1 @ W2 + b2 + x
    mfma_gemm<<<dim3(DIMD / 64, MB64), 256, 0, stream>>>(ff1_bf, w2_t, b2_l, x, x, nullptr, M, DIMD, MLPD, 0);
  }

  // final: LN(x[:,0]) fp32 -> head
  ln_kernel<<<BATCH, 256, 0, stream>>>(x, hln_g, hln_b, nullptr, hfin, (long)NTOK * DIMD);
  gemm_kernel<<<dim3((NCLSD + 15) / 16, 1), thr16, 0, stream>>>(hfin, head_w, head_b, out, BATCH, NCLSD, DIMD);
}

// Round 4
// 574.511 us; speedup vs baseline: 4.1478x; 1.5273x over previous
//
#include <hip/hip_runtime.h>
#include <math.h>

// SparseViT forward. Round 4: dense scores via batched MFMA GEMM (bf16),
// attention kernel becomes score-reader + softmax + coalesced bf16 V-weighting.
// B=2, N=577, DIM=512, H=8, DH=64, DEPTH=2, MLP=2048, NCLS=1000, nc=145, ns=10

#define NTOK 577
#define DIMD 512
#define NH 8
#define DHD 64
#define NC 145
#define NSB 10
#define KSELD 4
#define SBD 64
#define CBD 16
#define CSD 4
#define SWD 32
#define MLPD 2048
#define NCLSD 1000
#define BATCH 2
#define QKVN 1536    // fused q|k|v columns
#define SFSTRIDE 592 // padded col stride of dense score plane
#define SCSTRIDE 160 // padded col stride of compressed score plane

typedef unsigned short ushort;
typedef __attribute__((ext_vector_type(8))) short short8;
typedef __attribute__((ext_vector_type(4))) short short4v;
typedef __attribute__((ext_vector_type(4))) float f32x4;

__device__ __forceinline__ ushort bf16_rne(float f) {
  union { float f; unsigned u; } v; v.f = f;
  unsigned u = v.u;
  unsigned r = (u + 0x7fffu + ((u >> 16) & 1u)) >> 16;
  return (ushort)r;
}
__device__ __forceinline__ float bf16_to_f(ushort s) {
  union { unsigned u; float f; } v; v.u = ((unsigned)s) << 16;
  return v.f;
}
__device__ __forceinline__ int imin(int a, int b) { return a < b ? a : b; }
__device__ __forceinline__ int imax(int a, int b) { return a > b ? a : b; }

// ---------------- patch embed + cls + pos ----------------
__global__ void patch_kernel(const float* __restrict__ img, const float* __restrict__ pw,
                             const float* __restrict__ pb, const float* __restrict__ pos,
                             const float* __restrict__ cls, float* __restrict__ x) {
  int idx = blockIdx.x * 256 + threadIdx.x;
  const int total = BATCH * NTOK * DIMD;
  if (idx >= total) return;
  int d = idx & (DIMD - 1);
  int i = (idx / DIMD) % NTOK;
  int b = idx / (DIMD * NTOK);
  float val;
  if (i == 0) {
    val = cls[d];
  } else {
    int p = i - 1;
    val = pb[d];
#pragma unroll
    for (int c = 0; c < 3; ++c)
      val += img[b * 3 * 576 + c * 576 + p] * pw[c * DIMD + d];
  }
  x[idx] = val + pos[i * DIMD + d];
}

// ---------------- layernorm: writes bf16 and/or fp32 ----------------
__global__ void ln_kernel(const float* __restrict__ x, const float* __restrict__ g,
                          const float* __restrict__ bb, ushort* __restrict__ out_bf,
                          float* __restrict__ out_f, long rstride) {
  int row = blockIdx.x;
  const float* xr = x + (long)row * rstride;
  int t = threadIdx.x;
  float a = xr[t], c = xr[t + 256];
  __shared__ float s1[256], s2[256];
  s1[t] = a + c;
  s2[t] = a * a + c * c;
  __syncthreads();
  for (int off = 128; off > 0; off >>= 1) {
    if (t < off) { s1[t] += s1[t + off]; s2[t] += s2[t + off]; }
    __syncthreads();
  }
  float m = s1[0] * (1.0f / 512.0f);
  float var = s2[0] * (1.0f / 512.0f) - m * m;
  float r = rsqrtf(var + 1e-5f);
  float o0 = (a - m) * r * g[t] + bb[t];
  float o1 = (c - m) * r * g[t + 256] + bb[t + 256];
  if (out_bf) {
    out_bf[(long)row * DIMD + t] = bf16_rne(o0);
    out_bf[(long)row * DIMD + t + 256] = bf16_rne(o1);
  }
  if (out_f) {
    out_f[(long)row * DIMD + t] = o0;
    out_f[(long)row * DIMD + t + 256] = o1;
  }
}

// ---------------- weight transpose + fp32->bf16: W[K][N] -> Wt[Npad][K] ----------------
__global__ void wtrans_kernel(const float* __restrict__ W, ushort* __restrict__ Wt,
                              int K, int N) {
  __shared__ float tile[32][33];
  int k0 = blockIdx.y * 32, n0 = blockIdx.x * 32;
  int tx = threadIdx.x, ty = threadIdx.y;  // 32 x 8
#pragma unroll
  for (int r = 0; r < 32; r += 8)
    tile[ty + r][tx] = (n0 + tx < N) ? W[(long)(k0 + ty + r) * N + n0 + tx] : 0.f;
  __syncthreads();
#pragma unroll
  for (int r = 0; r < 32; r += 8) Wt[(long)(n0 + ty + r) * K + k0 + tx] = bf16_rne(tile[tx][ty + r]);
}

// ---------------- bf16 MFMA GEMM: C = act(A @ Bt^T + bias) + resid ----------------
__global__ __launch_bounds__(256) void mfma_gemm(
    const ushort* __restrict__ A, const ushort* __restrict__ Bt,
    const float* __restrict__ bias, const float* __restrict__ resid,
    float* __restrict__ Cf, ushort* __restrict__ Cbf,
    int M, int N, int K, int act) {
  __shared__ short As[64][72];
  __shared__ short Bs[64][72];
  int tid = threadIdx.x;
  int lane = tid & 63, wave = tid >> 6;
  int wm = wave >> 1, wn = wave & 1;
  int rowBase = blockIdx.y * 64, colBase = blockIdx.x * 64;
  int m = lane & 15, kg = lane >> 4;
  f32x4 acc[2][2] = {};
  for (int k0 = 0; k0 < K; k0 += 64) {
#pragma unroll
    for (int cc = 0; cc < 2; ++cc) {
      int c = tid * 2 + cc;
      int r = c >> 3, kc = c & 7;
      short8 av = {};
      int gr = rowBase + r;
      if (gr < M) av = *(const short8*)(A + (long)gr * K + k0 + kc * 8);
      *(short8*)&As[r][kc * 8] = av;
      short8 bv = *(const short8*)(Bt + (long)(colBase + r) * K + k0 + kc * 8);
      *(short8*)&Bs[r][kc * 8] = bv;
    }
    __syncthreads();
#pragma unroll
    for (int ks = 0; ks < 2; ++ks) {
      short8 a0 = *(const short8*)&As[wm * 32 + m][ks * 32 + kg * 8];
      short8 a1 = *(const short8*)&As[wm * 32 + 16 + m][ks * 32 + kg * 8];
      short8 b0 = *(const short8*)&Bs[wn * 32 + m][ks * 32 + kg * 8];
      short8 b1 = *(const short8*)&Bs[wn * 32 + 16 + m][ks * 32 + kg * 8];
      acc[0][0] = __builtin_amdgcn_mfma_f32_16x16x32_bf16(a0, b0, acc[0][0], 0, 0, 0);
      acc[0][1] = __builtin_amdgcn_mfma_f32_16x16x32_bf16(a0, b1, acc[0][1], 0, 0, 0);
      acc[1][0] = __builtin_amdgcn_mfma_f32_16x16x32_bf16(a1, b0, acc[1][0], 0, 0, 0);
      acc[1][1] = __builtin_amdgcn_mfma_f32_16x16x32_bf16(a1, b1, acc[1][1], 0, 0, 0);
    }
    __syncthreads();
  }
#pragma unroll
  for (int mt = 0; mt < 2; ++mt)
#pragma unroll
    for (int nt = 0; nt < 2; ++nt) {
      int col = colBase + wn * 32 + nt * 16 + (lane & 15);
#pragma unroll
      for (int r = 0; r < 4; ++r) {
        int row = rowBase + wm * 32 + mt * 16 + (lane >> 4) * 4 + r;
        if (row < M) {
          float v = acc[mt][nt][r];
          if (bias) v += bias[col];
          if (act == 1) {
            float u = 0.7978845608028654f * (v + 0.044715f * v * v * v);
            v = 0.5f * v * (1.f + tanhf(u));
          } else if (act == 2) {
            v = 1.f / (1.f + __expf(-v));
          }
          if (resid) v += resid[(long)row * N + col];
          if (Cf) Cf[(long)row * N + col] = v;
          else Cbf[(long)row * N + col] = bf16_rne(v);
        }
      }
    }
}

// ---------------- batched score GEMM: S[z][i][j] = scale * (q_i . key_j), bf16 out ----------------
// A rows: qkv fp32, row i at (b*NTOK+i)*QKVN + h*64.
// B rows: useCk ? ckb bf16 packed [z*NC + j][64] : qkv fp32 k-rows (+512 offset).
__global__ __launch_bounds__(256) void score_kernel(
    const float* __restrict__ qkv, const ushort* __restrict__ ckb,
    ushort* __restrict__ S, int Nvalid, int sStride, int useCk, float scale) {
  __shared__ short As[64][72];
  __shared__ short Bs[64][72];
  int z = blockIdx.z;
  int b = z >> 3, h = z & 7;
  int i0 = blockIdx.y * 64, j0 = blockIdx.x * 64;
  int tid = threadIdx.x;
  int lane = tid & 63, wave = tid >> 6;
  int wm = wave >> 1, wn = wave & 1;
  const float* aBase = qkv + (long)b * NTOK * QKVN + h * 64;
  const float* bBase = aBase + 512;
  const ushort* cBase = ckb + (long)z * NC * DHD;

  // stage A (64 q-rows) and B (64 key-rows) as bf16
#pragma unroll
  for (int rep = 0; rep < 4; ++rep) {
    int row = rep * 16 + (tid >> 4);
    int c4 = tid & 15;
    int gi = i0 + row;
    float4 av = {0.f, 0.f, 0.f, 0.f};
    if (gi < NTOK) av = *(const float4*)(aBase + (long)gi * QKVN + c4 * 4);
    short4v a16;
    a16.x = (short)bf16_rne(av.x); a16.y = (short)bf16_rne(av.y);
    a16.z = (short)bf16_rne(av.z); a16.w = (short)bf16_rne(av.w);
    *(short4v*)&As[row][c4 * 4] = a16;
    int gj = j0 + row;
    short4v b16 = {};
    if (useCk) {
      if (gj < Nvalid) b16 = *(const short4v*)(cBase + (long)gj * DHD + c4 * 4);
    } else {
      if (gj < Nvalid) {
        float4 bv = *(const float4*)(bBase + (long)gj * QKVN + c4 * 4);
        b16.x = (short)bf16_rne(bv.x); b16.y = (short)bf16_rne(bv.y);
        b16.z = (short)bf16_rne(bv.z); b16.w = (short)bf16_rne(bv.w);
      }
    }
    *(short4v*)&Bs[row][c4 * 4] = b16;
  }
  __syncthreads();

  int m = lane & 15, kg = lane >> 4;
  f32x4 acc[2][2] = {};
#pragma unroll
  for (int ks = 0; ks < 2; ++ks) {
    short8 a0 = *(const short8*)&As[wm * 32 + m][ks * 32 + kg * 8];
    short8 a1 = *(const short8*)&As[wm * 32 + 16 + m][ks * 32 + kg * 8];
    short8 b0 = *(const short8*)&Bs[wn * 32 + m][ks * 32 + kg * 8];
    short8 b1 = *(const short8*)&Bs[wn * 32 + 16 + m][ks * 32 + kg * 8];
    acc[0][0] = __builtin_amdgcn_mfma_f32_16x16x32_bf16(a0, b0, acc[0][0], 0, 0, 0);
    acc[0][1] = __builtin_amdgcn_mfma_f32_16x16x32_bf16(a0, b1, acc[0][1], 0, 0, 0);
    acc[1][0] = __builtin_amdgcn_mfma_f32_16x16x32_bf16(a1, b0, acc[1][0], 0, 0, 0);
    acc[1][1] = __builtin_amdgcn_mfma_f32_16x16x32_bf16(a1, b1, acc[1][1], 0, 0, 0);
  }
  ushort* Sz = S + (long)z * NTOK * sStride;
#pragma unroll
  for (int mt = 0; mt < 2; ++mt)
#pragma unroll
    for (int nt = 0; nt < 2; ++nt) {
      int col = j0 + wn * 32 + nt * 16 + (lane & 15);
#pragma unroll
      for (int r = 0; r < 4; ++r) {
        int row = i0 + wm * 32 + mt * 16 + (lane >> 4) * 4 + r;
        if (row < NTOK && col < Nvalid)
          Sz[(long)row * sStride + col] = bf16_rne(acc[mt][nt][r] * scale);
      }
    }
}

// ---------------- v cast fp32 -> bf16 mirror ----------------
__global__ void vcast_kernel(const float* __restrict__ qkv, ushort* __restrict__ vb) {
  int idx = blockIdx.x * 256 + threadIdx.x;   // float4 granularity over B*NTOK*512
  int row = idx >> 7;
  int c4 = idx & 127;
  float4 v = *(const float4*)(qkv + (long)row * QKVN + 1024 + c4 * 4);
  short4v o;
  o.x = (short)bf16_rne(v.x); o.y = (short)bf16_rne(v.y);
  o.z = (short)bf16_rne(v.z); o.w = (short)bf16_rne(v.w);
  *(short4v*)(vb + (long)row * DIMD + c4 * 4) = o;
}

// ---------------- small fp32 GEMM (head only) ----------------
__global__ void gemm_kernel(const float* __restrict__ A, const float* __restrict__ Bm,
                            const float* __restrict__ bias, float* __restrict__ C,
                            int M, int Nn, int K) {
  __shared__ float As[16][17], Bs[16][17];
  int tx = threadIdx.x, ty = threadIdx.y;
  int row = blockIdx.y * 16 + ty;
  int col = blockIdx.x * 16 + tx;
  float acc = 0.f;
  for (int k0 = 0; k0 < K; k0 += 16) {
    As[ty][tx] = (row < M) ? A[(long)row * K + k0 + tx] : 0.f;
    Bs[ty][tx] = (col < Nn) ? Bm[(long)(k0 + ty) * Nn + col] : 0.f;
    __syncthreads();
#pragma unroll
    for (int kk = 0; kk < 16; ++kk) acc += As[ty][kk] * Bs[kk][tx];
    __syncthreads();
  }
  if (row < M && col < Nn) {
    if (bias) acc += bias[col];
    C[(long)row * Nn + col] = acc;
  }
}

// ---------------- kw/vw build: row r=(b,h,j), cols t*64+d (bf16) ----------------
__global__ void kwbuild_kernel(const float* __restrict__ qkv,
                               const float* __restrict__ kpe, const float* __restrict__ vpe,
                               ushort* __restrict__ kwm, ushort* __restrict__ vwm) {
  int r = blockIdx.x;               // 0..2319
  int j = r % NC;
  int bh = r / NC;
  int h = bh & 7, b = bh >> 3;
  int t = threadIdx.x >> 4;         // 0..15 window slot
  int d4 = threadIdx.x & 15;        // float4 index within DH
  int tok = j * CSD + t;
  float4 kv = {0.f, 0.f, 0.f, 0.f}, vv = kv;
  if (tok < NTOK) {
    long base = (long)(b * NTOK + tok) * QKVN + h * DHD + d4 * 4;
    kv = *(const float4*)(qkv + base + 512);
    vv = *(const float4*)(qkv + base + 1024);
  }
  float4 kp = *(const float4*)(kpe + t * DHD + d4 * 4);
  float4 vp = *(const float4*)(vpe + t * DHD + d4 * 4);
  short4v ko, vo;
  ko.x = (short)bf16_rne(kv.x + kp.x); ko.y = (short)bf16_rne(kv.y + kp.y);
  ko.z = (short)bf16_rne(kv.z + kp.z); ko.w = (short)bf16_rne(kv.w + kp.w);
  vo.x = (short)bf16_rne(vv.x + vp.x); vo.y = (short)bf16_rne(vv.y + vp.y);
  vo.z = (short)bf16_rne(vv.z + vp.z); vo.w = (short)bf16_rne(vv.w + vp.w);
  long ob = (long)r * 1024 + t * DHD + d4 * 4;
  *(short4v*)(kwm + ob) = ko;
  *(short4v*)(vwm + ob) = vo;
}

// ---------------- fused sparse attention v5: score-reader + bf16 V weighting ----------------
__global__ __launch_bounds__(256, 4) void attn_kernel(
    const ushort* __restrict__ Sf, const ushort* __restrict__ Sc,
    const float* __restrict__ g, const ushort* __restrict__ cvb,
    const ushort* __restrict__ vb, ushort* __restrict__ comb) {
  int qt = blockIdx.x % NC;          // 145 tiles of 4 queries
  int bh = blockIdx.x / NC;
  int h = bh & 7, b = bh >> 3;
  int tid = threadIdx.x, lane = tid & 63, w = tid >> 6;
  int i0 = qt * 4 + w;
  int i = imin(i0, NTOK - 1);
  bool valid = (i0 < NTOK);
  int z = b * NH + h;

  __shared__ float scL[4][192];
  __shared__ float ssL[4][256];
  __shared__ float swL[4][32];
  __shared__ float impL[4][16];
  __shared__ int selL[4][KSELD];
  float* sc = scL[w]; float* ss = ssL[w];
  float* swv = swL[w]; float* imp = impL[w]; int* sel = selL[w];

  const ushort* scRow = Sc + ((long)z * NTOK + i) * SCSTRIDE;
  const ushort* sfRow = Sf + ((long)z * NTOK + i) * SFSTRIDE;
  const ushort* cvz = cvb + (long)z * NC * DHD;
  const ushort* vbz = vb + (long)b * NTOK * DIMD + h * DHD;

  // ---- compressed branch ----
  float e[3], mC = -1e30f;
#pragma unroll
  for (int c = 0; c < 3; ++c) {
    int j = c * 64 + lane;
    int jc = imin(j, NC - 1);
    float s = bf16_to_f(scRow[jc]);
    s = (j < NC) ? s : -1e30f;
    e[c] = s;
    mC = fmaxf(mC, s);
  }
#pragma unroll
  for (int msk = 1; msk < 64; msk <<= 1) mC = fmaxf(mC, __shfl_xor(mC, msk, 64));
  float sumC = 0.f;
#pragma unroll
  for (int c = 0; c < 3; ++c) {
    float ev = (e[c] > -1e29f) ? __expf(e[c] - mC) : 0.f;
    sc[c * 64 + lane] = ev;
    sumC += ev;
  }
#pragma unroll
  for (int msk = 1; msk < 64; msk <<= 1) sumC += __shfl_xor(sumC, msk, 64);
  __syncthreads();

  // out_c (lane = d), 4 accumulators for load pipelining
  float o0 = 0.f, o1 = 0.f, o2 = 0.f, o3 = 0.f;
  for (int j = 0; j < 144; j += 4) {
    o0 += sc[j]     * bf16_to_f(cvz[(j)     * DHD + lane]);
    o1 += sc[j + 1] * bf16_to_f(cvz[(j + 1) * DHD + lane]);
    o2 += sc[j + 2] * bf16_to_f(cvz[(j + 2) * DHD + lane]);
    o3 += sc[j + 3] * bf16_to_f(cvz[(j + 3) * DHD + lane]);
  }
  float oc = (o0 + o1 + o2 + o3 + sc[144] * bf16_to_f(cvz[144 * DHD + lane])) / sumC;

  // ---- importance + top-k:  centers(j)==s  <=>  j in [16s-2, 16s+13] ----
  if (lane < NSB) {
    int lo = imax(0, 16 * lane - 2), hi = imin(NC - 1, 16 * lane + 13);
    float s = 0.f;
    for (int j = lo; j <= hi; ++j) s += sc[j];
    imp[lane] = s;
  }
  __syncthreads();
  if (lane == 0) {
    unsigned used = 0;
    for (int r = 0; r < KSELD; ++r) {
      int bi = 0; float bv = -1e30f;
      for (int s = 0; s < NSB; ++s)
        if (!((used >> s) & 1u) && imp[s] > bv) { bv = imp[s]; bi = s; }
      used |= 1u << bi;
      sel[r] = bi;
    }
  }
  __syncthreads();

  // ---- selected blocks: read dense scores (coalesced) ----
  float es[4], mS = -1e30f;
#pragma unroll
  for (int c = 0; c < 4; ++c) {
    int tok = sel[c] * SBD + lane;
    int tokc = imin(tok, NTOK - 1);
    float s = bf16_to_f(sfRow[tokc]);
    s = (tok < NTOK) ? s : -1e30f;
    es[c] = s;
    mS = fmaxf(mS, s);
  }
#pragma unroll
  for (int msk = 1; msk < 64; msk <<= 1) mS = fmaxf(mS, __shfl_xor(mS, msk, 64));
  float sumS = 0.f;
#pragma unroll
  for (int c = 0; c < 4; ++c) {
    float ev = (es[c] > -1e29f) ? __expf(es[c] - mS) : 0.f;
    ss[c * 64 + lane] = ev;
    sumS += ev;
  }
#pragma unroll
  for (int msk = 1; msk < 64; msk <<= 1) sumS += __shfl_xor(sumS, msk, 64);
  __syncthreads();

  // out_s (lane = d), unrolled x4
  float t0 = 0.f, t1 = 0.f, t2 = 0.f, t3 = 0.f;
  for (int kk = 0; kk < 256; kk += 4) {
    int b0i = sel[(kk) >> 6] * SBD + ((kk) & 63);
    int b1i = sel[(kk + 1) >> 6] * SBD + ((kk + 1) & 63);
    int b2i = sel[(kk + 2) >> 6] * SBD + ((kk + 2) & 63);
    int b3i = sel[(kk + 3) >> 6] * SBD + ((kk + 3) & 63);
    t0 += ss[kk]     * bf16_to_f(vbz[(long)imin(b0i, NTOK - 1) * DIMD + lane]);
    t1 += ss[kk + 1] * bf16_to_f(vbz[(long)imin(b1i, NTOK - 1) * DIMD + lane]);
    t2 += ss[kk + 2] * bf16_to_f(vbz[(long)imin(b2i, NTOK - 1) * DIMD + lane]);
    t3 += ss[kk + 3] * bf16_to_f(vbz[(long)imin(b3i, NTOK - 1) * DIMD + lane]);
  }
  float os = (t0 + t1 + t2 + t3) / sumS;

  // ---- sliding window: both 32-halves duplicate, butterfly over 32 ----
  float sw_s;
  {
    int pos = i + (lane & 31) - SWD / 2;
    int posc = imin(imax(pos, 0), NTOK - 1);
    float s = bf16_to_f(sfRow[posc]);
    sw_s = (pos >= 0 && pos < NTOK) ? s : -1e30f;
  }
  float mW = sw_s;
#pragma unroll
  for (int msk = 1; msk < 32; msk <<= 1) mW = fmaxf(mW, __shfl_xor(mW, msk, 64));
  float ew = (sw_s > -1e29f) ? __expf(sw_s - mW) : 0.f;
  float sumW = ew;
#pragma unroll
  for (int msk = 1; msk < 32; msk <<= 1) sumW += __shfl_xor(sumW, msk, 64);
  if (lane < SWD) swv[lane] = ew;
  __syncthreads();

  // out_w (lane = d), unrolled x4
  float w0 = 0.f, w1 = 0.f, w2 = 0.f, w3 = 0.f;
  for (int t = 0; t < SWD; t += 4) {
    int p0 = imin(imax(i + t - 16, 0), NTOK - 1);
    int p1 = imin(imax(i + t - 15, 0), NTOK - 1);
    int p2 = imin(imax(i + t - 14, 0), NTOK - 1);
    int p3 = imin(imax(i + t - 13, 0), NTOK - 1);
    w0 += swv[t]     * bf16_to_f(vbz[(long)p0 * DIMD + lane]);
    w1 += swv[t + 1] * bf16_to_f(vbz[(long)p1 * DIMD + lane]);
    w2 += swv[t + 2] * bf16_to_f(vbz[(long)p2 * DIMD + lane]);
    w3 += swv[t + 3] * bf16_to_f(vbz[(long)p3 * DIMD + lane]);
  }
  float ow = (w0 + w1 + w2 + w3) / sumW;

  // ---- gate combine + store bf16 ----
  const float* gp = g + (long)(b * NTOK + i) * 64 + h * 3;
  float val = gp[0] * oc + gp[1] * os + gp[2] * ow;
  if (valid) comb[(long)(b * NTOK + i) * DIMD + h * DHD + lane] = bf16_rne(val);
}

extern "C" void kernel_launch(void* const* d_in, const int* in_sizes, int n_in,
                              void* d_out, int out_size, void* d_ws, size_t ws_size,
                              hipStream_t stream) {
  const float* img     = (const float*)d_in[0];
  const float* patch_w = (const float*)d_in[1];
  const float* patch_b = (const float*)d_in[2];
  const float* pos_emb = (const float*)d_in[3];
  const float* cls_tok = (const float*)d_in[4];
  const float* ln1_g   = (const float*)d_in[5];
  const float* ln1_b   = (const float*)d_in[6];
  const float* Wq      = (const float*)d_in[7];
  const float* Wk      = (const float*)d_in[8];
  const float* Wv      = (const float*)d_in[9];
  const float* Wg      = (const float*)d_in[10];
  const float* Wo      = (const float*)d_in[11];
  const float* kpe     = (const float*)d_in[12];
  const float* vpe     = (const float*)d_in[13];
  const float* Wkc     = (const float*)d_in[14];
  const float* Wvc     = (const float*)d_in[15];
  const float* ln2_g   = (const float*)d_in[16];
  const float* ln2_b   = (const float*)d_in[17];
  const float* ff_w1   = (const float*)d_in[18];
  const float* ff_b1   = (const float*)d_in[19];
  const float* ff_w2   = (const float*)d_in[20];
  const float* ff_b2   = (const float*)d_in[21];
  const float* hln_g   = (const float*)d_in[22];
  const float* hln_b   = (const float*)d_in[23];
  const float* head_w  = (const float*)d_in[24];
  const float* head_b  = (const float*)d_in[25];
  float* out = (float*)d_out;

  // ---- workspace carve (~49 MB) ----
  char* p = (char*)d_ws;
  const long MROW = (long)BATCH * NTOK;            // 1154
  float* x       = (float*)p;  p += MROW * DIMD * 4;
  float* qkv     = (float*)p;  p += MROW * QKVN * 4;
  ushort* h_bf   = (ushort*)p; p += MROW * DIMD * 2;
  ushort* comb_bf= (ushort*)p; p += MROW * DIMD * 2;
  ushort* ff1_bf = (ushort*)p; p += MROW * MLPD * 2;
  float* gb      = (float*)p;  p += MROW * 64 * 4;
  ushort* ckb    = (ushort*)p; p += (long)BATCH * NH * NC * DHD * 2;
  ushort* cvb    = (ushort*)p; p += (long)BATCH * NH * NC * DHD * 2;
  ushort* vbuf   = (ushort*)p; p += MROW * DIMD * 2;
  ushort* Sf     = (ushort*)p; p += (long)BATCH * NH * NTOK * SFSTRIDE * 2;  // 10.9 MB
  ushort* Scb    = (ushort*)p; p += (long)BATCH * NH * NTOK * SCSTRIDE * 2;  // 3.0 MB
  float* hfin    = (float*)p;  p += BATCH * DIMD * 4;
  ushort* wqkv_t = (ushort*)p; p += (long)QKVN * DIMD * 2;
  ushort* wo_t   = (ushort*)p; p += (long)DIMD * DIMD * 2;
  ushort* w1_t   = (ushort*)p; p += (long)MLPD * DIMD * 2;
  ushort* w2_t   = (ushort*)p; p += (long)DIMD * MLPD * 2;
  ushort* wg_t   = (ushort*)p; p += (long)64 * DIMD * 2;
  ushort* wkc_t  = (ushort*)p; p += (long)64 * 1024 * 2;
  ushort* wvc_t  = (ushort*)p; p += (long)64 * 1024 * 2;
  ushort* kwm    = (ushort*)p; p += (long)BATCH * NH * NC * 1024 * 2;
  ushort* vwm    = (ushort*)p; p += (long)BATCH * NH * NC * 1024 * 2;

  const int M = (int)MROW;                  // 1154
  const int MB64 = (M + 63) / 64;           // 19
  const int MCK = BATCH * NH * NC;          // 2320
  const float scale = 0.125f;
  dim3 thr16(16, 16), thrT(32, 8);

  patch_kernel<<<(M * DIMD + 255) / 256, 256, 0, stream>>>(img, patch_w, patch_b, pos_emb, cls_tok, x);

  for (int l = 0; l < 2; ++l) {
    const float* Wq_l  = Wq + (long)l * DIMD * DIMD;
    const float* Wk_l  = Wk + (long)l * DIMD * DIMD;
    const float* Wv_l  = Wv + (long)l * DIMD * DIMD;
    const float* Wg_l  = Wg + (long)l * DIMD * 3 * NH;
    const float* Wo_l  = Wo + (long)l * DIMD * DIMD;
    const float* kpe_l = kpe + (long)l * CBD * DHD;
    const float* vpe_l = vpe + (long)l * CBD * DHD;
    const float* Wkc_l = Wkc + (long)l * CBD * DHD * DHD;
    const float* Wvc_l = Wvc + (long)l * CBD * DHD * DHD;
    const float* w1_l  = ff_w1 + (long)l * DIMD * MLPD;
    const float* b1_l  = ff_b1 + (long)l * MLPD;
    const float* w2_l  = ff_w2 + (long)l * MLPD * DIMD;
    const float* b2_l  = ff_b2 + (long)l * DIMD;

    // weight transposes -> bf16
    wtrans_kernel<<<dim3(16, 16), thrT, 0, stream>>>(Wq_l, wqkv_t, DIMD, DIMD);
    wtrans_kernel<<<dim3(16, 16), thrT, 0, stream>>>(Wk_l, wqkv_t + 512 * DIMD, DIMD, DIMD);
    wtrans_kernel<<<dim3(16, 16), thrT, 0, stream>>>(Wv_l, wqkv_t + 1024 * DIMD, DIMD, DIMD);
    wtrans_kernel<<<dim3(16, 16), thrT, 0, stream>>>(Wo_l, wo_t, DIMD, DIMD);
    wtrans_kernel<<<dim3(64, 16), thrT, 0, stream>>>(w1_l, w1_t, DIMD, MLPD);
    wtrans_kernel<<<dim3(16, 64), thrT, 0, stream>>>(w2_l, w2_t, MLPD, DIMD);
    wtrans_kernel<<<dim3(2, 16), thrT, 0, stream>>>(Wg_l, wg_t, DIMD, 3 * NH);
    wtrans_kernel<<<dim3(2, 32), thrT, 0, stream>>>(Wkc_l, wkc_t, 1024, DHD);
    wtrans_kernel<<<dim3(2, 32), thrT, 0, stream>>>(Wvc_l, wvc_t, 1024, DHD);

    // h = LN1(x) -> bf16
    ln_kernel<<<M, 256, 0, stream>>>(x, ln1_g + (long)l * DIMD, ln1_b + (long)l * DIMD, h_bf, nullptr, DIMD);
    // qkv = h @ [Wq|Wk|Wv]  (fp32 out)
    mfma_gemm<<<dim3(QKVN / 64, MB64), 256, 0, stream>>>(h_bf, wqkv_t, nullptr, nullptr, qkv, nullptr, M, QKVN, DIMD, 0);
    // gates: sigmoid(h @ Wg) padded to 64 cols
    mfma_gemm<<<dim3(1, MB64), 256, 0, stream>>>(h_bf, wg_t, nullptr, nullptr, gb, nullptr, M, 64, DIMD, 2);
    // v bf16 mirror
    vcast_kernel<<<(int)(MROW * DIMD / 4 / 256), 256, 0, stream>>>(qkv, vbuf);
    // kw/vw matrices (bf16) then ck/cv GEMMs -> bf16
    kwbuild_kernel<<<MCK, 256, 0, stream>>>(qkv, kpe_l, vpe_l, kwm, vwm);
    mfma_gemm<<<dim3(1, (MCK + 63) / 64), 256, 0, stream>>>(kwm, wkc_t, nullptr, nullptr, nullptr, ckb, MCK, 64, 1024, 0);
    mfma_gemm<<<dim3(1, (MCK + 63) / 64), 256, 0, stream>>>(vwm, wvc_t, nullptr, nullptr, nullptr, cvb, MCK, 64, 1024, 0);
    // dense scores S_full and compressed scores S_c (bf16)
    score_kernel<<<dim3(10, 10, BATCH * NH), 256, 0, stream>>>(qkv, ckb, Sf, NTOK, SFSTRIDE, 0, scale);
    score_kernel<<<dim3(3, 10, BATCH * NH), 256, 0, stream>>>(qkv, ckb, Scb, NC, SCSTRIDE, 1, scale);
    // fused sparse attention -> comb bf16
    attn_kernel<<<BATCH * NH * NC, 256, 0, stream>>>(Sf, Scb, gb, cvb, vbuf, comb_bf);
    // x = comb @ Wo + x
    mfma_gemm<<<dim3(DIMD / 64, MB64), 256, 0, stream>>>(comb_bf, wo_t, nullptr, x, x, nullptr, M, DIMD, DIMD, 0);
    // h = LN2(x) -> bf16
    ln_kernel<<<M, 256, 0, stream>>>(x, ln2_g + (long)l * DIMD, ln2_b + (long)l * DIMD, h_bf, nullptr, DIMD);
    // ff1 = gelu(h @ W1 + b1) -> bf16
    mfma_gemm<<<dim3(MLPD / 64, MB64), 256, 0, stream>>>(h_bf, w1_t, b1_l, nullptr, nullptr, ff1_bf, M, MLPD, DIMD, 1);
    // x = ff1 @ W2 + b2 + x
    mfma_gemm<<<dim3(DIMD / 64, MB64), 256, 0, stream>>>(ff1_bf, w2_t, b2_l, x, x, nullptr, M, DIMD, MLPD, 0);
  }

  // final: LN(x[:,0]) fp32 -> head
  ln_kernel<<<BATCH, 256, 0, stream>>>(x, hln_g, hln_b, nullptr, hfin, (long)NTOK * DIMD);
  gemm_kernel<<<dim3((NCLSD + 15) / 16, 1), thr16, 0, stream>>>(hfin, head_w, head_b, out, BATCH, NCLSD, DIMD);
}

// Round 5
// 462.268 us; speedup vs baseline: 5.1549x; 1.2428x over previous
//
#include <hip/hip_runtime.h>
#include <math.h>

// SparseViT forward. Round 5: attention P.V moved to MFMA (prob_kernel writes
// gated dense P; pv_gemm = P @ [V;CV]); single wtrans dispatch/layer; bf16 qkv.
// B=2, N=577, DIM=512, H=8, DH=64, DEPTH=2, MLP=2048, NCLS=1000, nc=145, ns=10

#define NTOK 577
#define DIMD 512
#define NH 8
#define DHD 64
#define NC 145
#define NSB 10
#define KSELD 4
#define SBD 64
#define CBD 16
#define CSD 4
#define SWD 32
#define MLPD 2048
#define NCLSD 1000
#define BATCH 2
#define QKVN 1536    // fused q|k|v columns
#define SFSTRIDE 592 // padded col stride of dense score plane
#define SCSTRIDE 160 // padded col stride of compressed score plane
#define PSTRIDE 832  // P row width: 640 token cols + 192 compressed cols (13*64)

typedef unsigned short ushort;
typedef __attribute__((ext_vector_type(8))) short short8;
typedef __attribute__((ext_vector_type(4))) short short4v;
typedef __attribute__((ext_vector_type(4))) float f32x4;

__device__ __forceinline__ ushort bf16_rne(float f) {
  union { float f; unsigned u; } v; v.f = f;
  unsigned u = v.u;
  unsigned r = (u + 0x7fffu + ((u >> 16) & 1u)) >> 16;
  return (ushort)r;
}
__device__ __forceinline__ float bf16_to_f(ushort s) {
  union { unsigned u; float f; } v; v.u = ((unsigned)s) << 16;
  return v.f;
}
__device__ __forceinline__ int imin(int a, int b) { return a < b ? a : b; }
__device__ __forceinline__ int imax(int a, int b) { return a > b ? a : b; }

// ---------------- patch embed + cls + pos ----------------
__global__ void patch_kernel(const float* __restrict__ img, const float* __restrict__ pw,
                             const float* __restrict__ pb, const float* __restrict__ pos,
                             const float* __restrict__ cls, float* __restrict__ x) {
  int idx = blockIdx.x * 256 + threadIdx.x;
  const int total = BATCH * NTOK * DIMD;
  if (idx >= total) return;
  int d = idx & (DIMD - 1);
  int i = (idx / DIMD) % NTOK;
  int b = idx / (DIMD * NTOK);
  float val;
  if (i == 0) {
    val = cls[d];
  } else {
    int p = i - 1;
    val = pb[d];
#pragma unroll
    for (int c = 0; c < 3; ++c)
      val += img[b * 3 * 576 + c * 576 + p] * pw[c * DIMD + d];
  }
  x[idx] = val + pos[i * DIMD + d];
}

// ---------------- layernorm: writes bf16 and/or fp32 ----------------
__global__ void ln_kernel(const float* __restrict__ x, const float* __restrict__ g,
                          const float* __restrict__ bb, ushort* __restrict__ out_bf,
                          float* __restrict__ out_f, long rstride) {
  int row = blockIdx.x;
  const float* xr = x + (long)row * rstride;
  int t = threadIdx.x;
  float a = xr[t], c = xr[t + 256];
  __shared__ float s1[256], s2[256];
  s1[t] = a + c;
  s2[t] = a * a + c * c;
  __syncthreads();
  for (int off = 128; off > 0; off >>= 1) {
    if (t < off) { s1[t] += s1[t + off]; s2[t] += s2[t + off]; }
    __syncthreads();
  }
  float m = s1[0] * (1.0f / 512.0f);
  float var = s2[0] * (1.0f / 512.0f) - m * m;
  float r = rsqrtf(var + 1e-5f);
  float o0 = (a - m) * r * g[t] + bb[t];
  float o1 = (c - m) * r * g[t + 256] + bb[t + 256];
  if (out_bf) {
    out_bf[(long)row * DIMD + t] = bf16_rne(o0);
    out_bf[(long)row * DIMD + t + 256] = bf16_rne(o1);
  }
  if (out_f) {
    out_f[(long)row * DIMD + t] = o0;
    out_f[(long)row * DIMD + t + 256] = o1;
  }
}

// ---------------- ALL weight transposes for one layer in ONE dispatch ----------------
// 3232 blocks of (32,8). Tile decode by blockIdx.x.
__global__ void wtrans_all_kernel(const float* __restrict__ Wq, const float* __restrict__ Wk,
                                  const float* __restrict__ Wv, const float* __restrict__ Wg,
                                  const float* __restrict__ Wo, const float* __restrict__ Wkc,
                                  const float* __restrict__ Wvc, const float* __restrict__ w1,
                                  const float* __restrict__ w2,
                                  ushort* __restrict__ wqkv_t, ushort* __restrict__ wo_t,
                                  ushort* __restrict__ w1_t, ushort* __restrict__ w2_t,
                                  ushort* __restrict__ wg_t, ushort* __restrict__ wkc_t,
                                  ushort* __restrict__ wvc_t) {
  __shared__ float tile[32][33];
  int t = blockIdx.x;
  const float* W; ushort* Wt; int K, N, bx, by;
  if (t < 768) {
    int which = t >> 8, rr = t & 255;
    W = which == 0 ? Wq : (which == 1 ? Wk : Wv);
    Wt = wqkv_t + which * 512 * 512;
    K = 512; N = 512; bx = rr & 15; by = rr >> 4;
  } else if (t < 1024) {
    int rr = t - 768; W = Wo; Wt = wo_t; K = 512; N = 512; bx = rr & 15; by = rr >> 4;
  } else if (t < 2048) {
    int rr = t - 1024; W = w1; Wt = w1_t; K = 512; N = 2048; bx = rr & 63; by = rr >> 6;
  } else if (t < 3072) {
    int rr = t - 2048; W = w2; Wt = w2_t; K = 2048; N = 512; bx = rr & 15; by = rr >> 4;
  } else if (t < 3104) {
    int rr = t - 3072; W = Wg; Wt = wg_t; K = 512; N = 24; bx = rr & 1; by = rr >> 1;
  } else if (t < 3168) {
    int rr = t - 3104; W = Wkc; Wt = wkc_t; K = 1024; N = 64; bx = rr & 1; by = rr >> 1;
  } else {
    int rr = t - 3168; W = Wvc; Wt = wvc_t; K = 1024; N = 64; bx = rr & 1; by = rr >> 1;
  }
  int k0 = by * 32, n0 = bx * 32;
  int tx = threadIdx.x, ty = threadIdx.y;
#pragma unroll
  for (int r = 0; r < 32; r += 8)
    tile[ty + r][tx] = (n0 + tx < N) ? W[(long)(k0 + ty + r) * N + n0 + tx] : 0.f;
  __syncthreads();
#pragma unroll
  for (int r = 0; r < 32; r += 8)
    Wt[(long)(n0 + ty + r) * K + k0 + tx] = bf16_rne(tile[tx][ty + r]);
}

// ---------------- bf16 MFMA GEMM: C = act(A @ Bt^T + bias) + resid ----------------
__global__ __launch_bounds__(256) void mfma_gemm(
    const ushort* __restrict__ A, const ushort* __restrict__ Bt,
    const float* __restrict__ bias, const float* __restrict__ resid,
    float* __restrict__ Cf, ushort* __restrict__ Cbf,
    int M, int N, int K, int act) {
  __shared__ short As[64][72];
  __shared__ short Bs[64][72];
  int tid = threadIdx.x;
  int lane = tid & 63, wave = tid >> 6;
  int wm = wave >> 1, wn = wave & 1;
  int rowBase = blockIdx.y * 64, colBase = blockIdx.x * 64;
  int m = lane & 15, kg = lane >> 4;
  f32x4 acc[2][2] = {};
  for (int k0 = 0; k0 < K; k0 += 64) {
#pragma unroll
    for (int cc = 0; cc < 2; ++cc) {
      int c = tid * 2 + cc;
      int r = c >> 3, kc = c & 7;
      short8 av = {};
      int gr = rowBase + r;
      if (gr < M) av = *(const short8*)(A + (long)gr * K + k0 + kc * 8);
      *(short8*)&As[r][kc * 8] = av;
      short8 bv = *(const short8*)(Bt + (long)(colBase + r) * K + k0 + kc * 8);
      *(short8*)&Bs[r][kc * 8] = bv;
    }
    __syncthreads();
#pragma unroll
    for (int ks = 0; ks < 2; ++ks) {
      short8 a0 = *(const short8*)&As[wm * 32 + m][ks * 32 + kg * 8];
      short8 a1 = *(const short8*)&As[wm * 32 + 16 + m][ks * 32 + kg * 8];
      short8 b0 = *(const short8*)&Bs[wn * 32 + m][ks * 32 + kg * 8];
      short8 b1 = *(const short8*)&Bs[wn * 32 + 16 + m][ks * 32 + kg * 8];
      acc[0][0] = __builtin_amdgcn_mfma_f32_16x16x32_bf16(a0, b0, acc[0][0], 0, 0, 0);
      acc[0][1] = __builtin_amdgcn_mfma_f32_16x16x32_bf16(a0, b1, acc[0][1], 0, 0, 0);
      acc[1][0] = __builtin_amdgcn_mfma_f32_16x16x32_bf16(a1, b0, acc[1][0], 0, 0, 0);
      acc[1][1] = __builtin_amdgcn_mfma_f32_16x16x32_bf16(a1, b1, acc[1][1], 0, 0, 0);
    }
    __syncthreads();
  }
#pragma unroll
  for (int mt = 0; mt < 2; ++mt)
#pragma unroll
    for (int nt = 0; nt < 2; ++nt) {
      int col = colBase + wn * 32 + nt * 16 + (lane & 15);
#pragma unroll
      for (int r = 0; r < 4; ++r) {
        int row = rowBase + wm * 32 + mt * 16 + (lane >> 4) * 4 + r;
        if (row < M) {
          float v = acc[mt][nt][r];
          if (bias) v += bias[col];
          if (act == 1) {
            float u = 0.7978845608028654f * (v + 0.044715f * v * v * v);
            v = 0.5f * v * (1.f + tanhf(u));
          } else if (act == 2) {
            v = 1.f / (1.f + __expf(-v));
          }
          if (resid) v += resid[(long)row * N + col];
          if (Cf) Cf[(long)row * N + col] = v;
          else Cbf[(long)row * N + col] = bf16_rne(v);
        }
      }
    }
}

// ---------------- batched score GEMM: merged dense (x<10) + compressed (x>=10) ----------------
__global__ __launch_bounds__(256) void score_kernel(
    const ushort* __restrict__ qkv_bf, const ushort* __restrict__ ckb,
    ushort* __restrict__ Sf, ushort* __restrict__ Scb, float scale) {
  __shared__ short As[64][72];
  __shared__ short Bs[64][72];
  int z = blockIdx.z;
  int b = z >> 3, h = z & 7;
  int i0 = blockIdx.y * 64;
  int xb = blockIdx.x;
  bool isC = xb >= 10;
  int j0 = (isC ? (xb - 10) : xb) * 64;
  int tid = threadIdx.x;
  int lane = tid & 63, wave = tid >> 6;
  int wm = wave >> 1, wn = wave & 1;
  const ushort* aBase = qkv_bf + (long)b * NTOK * QKVN + h * 64;
  const ushort* bBase = aBase + 512;
  const ushort* cBase = ckb + (long)z * NC * DHD;
#pragma unroll
  for (int rep = 0; rep < 4; ++rep) {
    int row = rep * 16 + (tid >> 4);
    int c4 = tid & 15;
    int gi = i0 + row;
    short4v a16 = {};
    if (gi < NTOK) a16 = *(const short4v*)(aBase + (long)gi * QKVN + c4 * 4);
    *(short4v*)&As[row][c4 * 4] = a16;
    int gj = j0 + row;
    short4v b16 = {};
    if (isC) {
      if (gj < NC) b16 = *(const short4v*)(cBase + (long)gj * DHD + c4 * 4);
    } else {
      if (gj < NTOK) b16 = *(const short4v*)(bBase + (long)gj * QKVN + c4 * 4);
    }
    *(short4v*)&Bs[row][c4 * 4] = b16;
  }
  __syncthreads();
  int m = lane & 15, kg = lane >> 4;
  f32x4 acc[2][2] = {};
#pragma unroll
  for (int ks = 0; ks < 2; ++ks) {
    short8 a0 = *(const short8*)&As[wm * 32 + m][ks * 32 + kg * 8];
    short8 a1 = *(const short8*)&As[wm * 32 + 16 + m][ks * 32 + kg * 8];
    short8 b0 = *(const short8*)&Bs[wn * 32 + m][ks * 32 + kg * 8];
    short8 b1 = *(const short8*)&Bs[wn * 32 + 16 + m][ks * 32 + kg * 8];
    acc[0][0] = __builtin_amdgcn_mfma_f32_16x16x32_bf16(a0, b0, acc[0][0], 0, 0, 0);
    acc[0][1] = __builtin_amdgcn_mfma_f32_16x16x32_bf16(a0, b1, acc[0][1], 0, 0, 0);
    acc[1][0] = __builtin_amdgcn_mfma_f32_16x16x32_bf16(a1, b0, acc[1][0], 0, 0, 0);
    acc[1][1] = __builtin_amdgcn_mfma_f32_16x16x32_bf16(a1, b1, acc[1][1], 0, 0, 0);
  }
  int nvalid = isC ? NC : NTOK;
  int sstride = isC ? SCSTRIDE : SFSTRIDE;
  ushort* Sz = (isC ? Scb : Sf) + (long)z * NTOK * sstride;
#pragma unroll
  for (int mt = 0; mt < 2; ++mt)
#pragma unroll
    for (int nt = 0; nt < 2; ++nt) {
      int col = j0 + wn * 32 + nt * 16 + (lane & 15);
#pragma unroll
      for (int r = 0; r < 4; ++r) {
        int row = i0 + wm * 32 + mt * 16 + (lane >> 4) * 4 + r;
        if (row < NTOK && col < nvalid)
          Sz[(long)row * sstride + col] = bf16_rne(acc[mt][nt][r] * scale);
      }
    }
}

// ---------------- kw/vw build from bf16 qkv ----------------
__global__ void kwbuild_kernel(const ushort* __restrict__ qkv_bf,
                               const float* __restrict__ kpe, const float* __restrict__ vpe,
                               ushort* __restrict__ kwm, ushort* __restrict__ vwm) {
  int r = blockIdx.x;               // 0..2319
  int j = r % NC;
  int bh = r / NC;
  int h = bh & 7, b = bh >> 3;
  int t = threadIdx.x >> 4;         // window slot 0..15
  int d4 = threadIdx.x & 15;        // group of 4 dims
  int tok = j * CSD + t;
  float k0 = 0.f, k1 = 0.f, k2 = 0.f, k3 = 0.f, v0 = 0.f, v1 = 0.f, v2 = 0.f, v3 = 0.f;
  if (tok < NTOK) {
    const ushort* base = qkv_bf + (long)(b * NTOK + tok) * QKVN + h * DHD + d4 * 4;
    short4v kv = *(const short4v*)(base + 512);
    short4v vv = *(const short4v*)(base + 1024);
    k0 = bf16_to_f((ushort)kv.x); k1 = bf16_to_f((ushort)kv.y);
    k2 = bf16_to_f((ushort)kv.z); k3 = bf16_to_f((ushort)kv.w);
    v0 = bf16_to_f((ushort)vv.x); v1 = bf16_to_f((ushort)vv.y);
    v2 = bf16_to_f((ushort)vv.z); v3 = bf16_to_f((ushort)vv.w);
  }
  float4 kp = *(const float4*)(kpe + t * DHD + d4 * 4);
  float4 vp = *(const float4*)(vpe + t * DHD + d4 * 4);
  short4v ko, vo;
  ko.x = (short)bf16_rne(k0 + kp.x); ko.y = (short)bf16_rne(k1 + kp.y);
  ko.z = (short)bf16_rne(k2 + kp.z); ko.w = (short)bf16_rne(k3 + kp.w);
  vo.x = (short)bf16_rne(v0 + vp.x); vo.y = (short)bf16_rne(v1 + vp.y);
  vo.z = (short)bf16_rne(v2 + vp.z); vo.w = (short)bf16_rne(v3 + vp.w);
  long ob = (long)r * 1024 + t * DHD + d4 * 4;
  *(short4v*)(kwm + ob) = ko;
  *(short4v*)(vwm + ob) = vo;
}

// ---------------- Vext^T build: Vt[z][d][kcol], kcol<640 tokens, 640+ = cv rows ----------------
__global__ void vtrans_kernel(const ushort* __restrict__ qkv_bf, const ushort* __restrict__ cvb,
                              ushort* __restrict__ Vt) {
  int kt = blockIdx.x;   // 0..12
  int z = blockIdx.y;    // 0..15
  int b = z >> 3, h = z & 7;
  __shared__ short tile[64][72];
  int tid = threadIdx.x;
  int r = tid >> 2, seg = tid & 3;  // 16 shorts per thread
  short8 a0 = {}, a1 = {};
  if (kt < 10) {
    int tok = kt * 64 + r;
    if (tok < NTOK) {
      const ushort* src = qkv_bf + (long)(b * NTOK + tok) * QKVN + 1024 + h * 64 + seg * 16;
      a0 = *(const short8*)src;
      a1 = *(const short8*)(src + 8);
    }
  } else {
    int cr = (kt - 10) * 64 + r;
    if (cr < NC) {
      const ushort* src = cvb + ((long)z * NC + cr) * DHD + seg * 16;
      a0 = *(const short8*)src;
      a1 = *(const short8*)(src + 8);
    }
  }
  *(short8*)&tile[r][seg * 16] = a0;
  *(short8*)&tile[r][seg * 16 + 8] = a1;
  __syncthreads();
  int d = tid >> 2;
  short8 o0, o1;
#pragma unroll
  for (int q = 0; q < 8; ++q) o0[q] = tile[seg * 16 + q][d];
#pragma unroll
  for (int q = 0; q < 8; ++q) o1[q] = tile[seg * 16 + 8 + q][d];
  ushort* dst = Vt + ((long)z * 64 + d) * PSTRIDE + kt * 64 + seg * 16;
  *(short8*)dst = o0;
  *(short8*)(dst + 8) = o1;
}

// ---------------- prob: softmax + top-k + gates -> dense gated P row (bf16) ----------------
__global__ __launch_bounds__(256, 4) void prob_kernel(
    const ushort* __restrict__ Sf, const ushort* __restrict__ Scb,
    const float* __restrict__ gb, ushort* __restrict__ P) {
  int qt = blockIdx.x % NC;
  int z = blockIdx.x / NC;
  int h = z & 7, b = z >> 3;
  int tid = threadIdx.x, lane = tid & 63, w = tid >> 6;
  int i0 = qt * 4 + w;
  bool valid = i0 < NTOK;
  int i = imin(i0, NTOK - 1);

  __shared__ float scL[4][192];
  __shared__ float ssL[4][256];
  __shared__ float swL[4][32];
  __shared__ float impL[4][16];
  __shared__ int selL[4][KSELD];
  float* sc = scL[w]; float* ss = ssL[w];
  float* swv = swL[w]; float* imp = impL[w]; int* sel = selL[w];

  const ushort* scRow = Scb + ((long)z * NTOK + i) * SCSTRIDE;
  const ushort* sfRow = Sf + ((long)z * NTOK + i) * SFSTRIDE;

  // ---- compressed softmax ----
  float e[3], mC = -1e30f;
#pragma unroll
  for (int c = 0; c < 3; ++c) {
    int j = c * 64 + lane;
    float s = bf16_to_f(scRow[imin(j, NC - 1)]);
    s = (j < NC) ? s : -1e30f;
    e[c] = s;
    mC = fmaxf(mC, s);
  }
#pragma unroll
  for (int msk = 1; msk < 64; msk <<= 1) mC = fmaxf(mC, __shfl_xor(mC, msk, 64));
  float sumC = 0.f;
#pragma unroll
  for (int c = 0; c < 3; ++c) {
    float ev = (e[c] > -1e29f) ? __expf(e[c] - mC) : 0.f;
    sc[c * 64 + lane] = ev;
    sumC += ev;
  }
#pragma unroll
  for (int msk = 1; msk < 64; msk <<= 1) sumC += __shfl_xor(sumC, msk, 64);
  __syncthreads();

  // ---- importance + top-k (centers(j)==s <=> j in [16s-2, 16s+13]) ----
  if (lane < NSB) {
    int lo = imax(0, 16 * lane - 2), hi = imin(NC - 1, 16 * lane + 13);
    float s = 0.f;
    for (int j = lo; j <= hi; ++j) s += sc[j];
    imp[lane] = s;
  }
  __syncthreads();
  if (lane == 0) {
    unsigned used = 0;
    for (int r = 0; r < KSELD; ++r) {
      int bi = 0; float bv = -1e30f;
      for (int s = 0; s < NSB; ++s)
        if (!((used >> s) & 1u) && imp[s] > bv) { bv = imp[s]; bi = s; }
      used |= 1u << bi;
      sel[r] = bi;
    }
  }
  __syncthreads();

  // ---- selected-block softmax ----
  float es[4], mS = -1e30f;
#pragma unroll
  for (int c = 0; c < 4; ++c) {
    int tok = sel[c] * SBD + lane;
    float s = bf16_to_f(sfRow[imin(tok, NTOK - 1)]);
    s = (tok < NTOK) ? s : -1e30f;
    es[c] = s;
    mS = fmaxf(mS, s);
  }
#pragma unroll
  for (int msk = 1; msk < 64; msk <<= 1) mS = fmaxf(mS, __shfl_xor(mS, msk, 64));
  float sumS = 0.f;
#pragma unroll
  for (int c = 0; c < 4; ++c) {
    float ev = (es[c] > -1e29f) ? __expf(es[c] - mS) : 0.f;
    ss[c * 64 + lane] = ev;
    sumS += ev;
  }
#pragma unroll
  for (int msk = 1; msk < 64; msk <<= 1) sumS += __shfl_xor(sumS, msk, 64);

  // ---- sliding window (both halves duplicate; butterfly over 32) ----
  float sw_s;
  {
    int pos = i + (lane & 31) - SWD / 2;
    float s = bf16_to_f(sfRow[imin(imax(pos, 0), NTOK - 1)]);
    sw_s = (pos >= 0 && pos < NTOK) ? s : -1e30f;
  }
  float mW = sw_s;
#pragma unroll
  for (int msk = 1; msk < 32; msk <<= 1) mW = fmaxf(mW, __shfl_xor(mW, msk, 64));
  float ew = (sw_s > -1e29f) ? __expf(sw_s - mW) : 0.f;
  float sumW = ew;
#pragma unroll
  for (int msk = 1; msk < 32; msk <<= 1) sumW += __shfl_xor(sumW, msk, 64);
  if (lane < SWD) swv[lane] = ew;
  __syncthreads();

  if (!valid) return;
  const float* gp = gb + (long)(b * NTOK + i) * 64 + h * 3;
  float rC = gp[0] / sumC, rS = gp[1] / sumS, rW = gp[2] / sumW;
  ushort* prow = P + ((long)z * NTOK + i0) * PSTRIDE;
#pragma unroll
  for (int c = 0; c < 10; ++c) {
    int col = c * 64 + lane;
    float val = 0.f;
#pragma unroll
    for (int r = 0; r < 4; ++r)
      if (sel[r] == c) val += rS * ss[r * 64 + lane];
    int t = col - i + 16;
    if (t >= 0 && t < SWD && col < NTOK) val += rW * swv[t];
    prow[col] = bf16_rne(val);
  }
#pragma unroll
  for (int c = 0; c < 3; ++c) {
    int j = c * 64 + lane;
    float val = (j < NC) ? rC * sc[j] : 0.f;
    prow[640 + j] = bf16_rne(val);
  }
}

// ---------------- PV GEMM: comb[b,i,h*64+d] = P[z] @ Vext[z] ----------------
__global__ __launch_bounds__(256) void pv_gemm(const ushort* __restrict__ P,
                                               const ushort* __restrict__ Vt,
                                               ushort* __restrict__ comb) {
  __shared__ short As[64][72];
  __shared__ short Bs[64][72];
  int z = blockIdx.y;
  int b = z >> 3, h = z & 7;
  int rowBase = blockIdx.x * 64;
  int tid = threadIdx.x;
  int lane = tid & 63, wave = tid >> 6;
  int wm = wave >> 1, wn = wave & 1;
  const ushort* Pz = P + (long)z * NTOK * PSTRIDE;
  const ushort* Vz = Vt + (long)z * 64 * PSTRIDE;
  int m = lane & 15, kg = lane >> 4;
  f32x4 acc[2][2] = {};
  for (int k0 = 0; k0 < PSTRIDE; k0 += 64) {
#pragma unroll
    for (int cc = 0; cc < 2; ++cc) {
      int c = tid * 2 + cc;
      int r = c >> 3, kc = c & 7;
      short8 av = {};
      int gr = rowBase + r;
      if (gr < NTOK) av = *(const short8*)(Pz + (long)gr * PSTRIDE + k0 + kc * 8);
      *(short8*)&As[r][kc * 8] = av;
      short8 bv = *(const short8*)(Vz + (long)r * PSTRIDE + k0 + kc * 8);
      *(short8*)&Bs[r][kc * 8] = bv;
    }
    __syncthreads();
#pragma unroll
    for (int ks = 0; ks < 2; ++ks) {
      short8 a0 = *(const short8*)&As[wm * 32 + m][ks * 32 + kg * 8];
      short8 a1 = *(const short8*)&As[wm * 32 + 16 + m][ks * 32 + kg * 8];
      short8 b0 = *(const short8*)&Bs[wn * 32 + m][ks * 32 + kg * 8];
      short8 b1 = *(const short8*)&Bs[wn * 32 + 16 + m][ks * 32 + kg * 8];
      acc[0][0] = __builtin_amdgcn_mfma_f32_16x16x32_bf16(a0, b0, acc[0][0], 0, 0, 0);
      acc[0][1] = __builtin_amdgcn_mfma_f32_16x16x32_bf16(a0, b1, acc[0][1], 0, 0, 0);
      acc[1][0] = __builtin_amdgcn_mfma_f32_16x16x32_bf16(a1, b0, acc[1][0], 0, 0, 0);
      acc[1][1] = __builtin_amdgcn_mfma_f32_16x16x32_bf16(a1, b1, acc[1][1], 0, 0, 0);
    }
    __syncthreads();
  }
#pragma unroll
  for (int mt = 0; mt < 2; ++mt)
#pragma unroll
    for (int nt = 0; nt < 2; ++nt) {
      int col = wn * 32 + nt * 16 + (lane & 15);
#pragma unroll
      for (int r = 0; r < 4; ++r) {
        int row = rowBase + wm * 32 + mt * 16 + (lane >> 4) * 4 + r;
        if (row < NTOK)
          comb[(long)(b * NTOK + row) * DIMD + h * 64 + col] = bf16_rne(acc[mt][nt][r]);
      }
    }
}

// ---------------- head: out[b][n] = LN-row . W[:,n] + bias ----------------
__global__ void head_kernel(const float* __restrict__ hfin, const float* __restrict__ W,
                            const float* __restrict__ bias, float* __restrict__ out) {
  __shared__ float hs[512];
  int bidx = blockIdx.y;
  int t = threadIdx.x;
  hs[t] = hfin[bidx * 512 + t];
  hs[t + 256] = hfin[bidx * 512 + t + 256];
  __syncthreads();
  int col = blockIdx.x * 256 + t;
  if (col < NCLSD) {
    float acc = bias[col];
#pragma unroll 8
    for (int k = 0; k < 512; ++k) acc += hs[k] * W[(long)k * NCLSD + col];
    out[bidx * NCLSD + col] = acc;
  }
}

extern "C" void kernel_launch(void* const* d_in, const int* in_sizes, int n_in,
                              void* d_out, int out_size, void* d_ws, size_t ws_size,
                              hipStream_t stream) {
  const float* img     = (const float*)d_in[0];
  const float* patch_w = (const float*)d_in[1];
  const float* patch_b = (const float*)d_in[2];
  const float* pos_emb = (const float*)d_in[3];
  const float* cls_tok = (const float*)d_in[4];
  const float* ln1_g   = (const float*)d_in[5];
  const float* ln1_b   = (const float*)d_in[6];
  const float* Wq      = (const float*)d_in[7];
  const float* Wk      = (const float*)d_in[8];
  const float* Wv      = (const float*)d_in[9];
  const float* Wg      = (const float*)d_in[10];
  const float* Wo      = (const float*)d_in[11];
  const float* kpe     = (const float*)d_in[12];
  const float* vpe     = (const float*)d_in[13];
  const float* Wkc     = (const float*)d_in[14];
  const float* Wvc     = (const float*)d_in[15];
  const float* ln2_g   = (const float*)d_in[16];
  const float* ln2_b   = (const float*)d_in[17];
  const float* ff_w1   = (const float*)d_in[18];
  const float* ff_b1   = (const float*)d_in[19];
  const float* ff_w2   = (const float*)d_in[20];
  const float* ff_b2   = (const float*)d_in[21];
  const float* hln_g   = (const float*)d_in[22];
  const float* hln_b   = (const float*)d_in[23];
  const float* head_w  = (const float*)d_in[24];
  const float* head_b  = (const float*)d_in[25];
  float* out = (float*)d_out;

  // ---- workspace carve (~47 MB) ----
  char* p = (char*)d_ws;
  const long MROW = (long)BATCH * NTOK;            // 1154
  float* x       = (float*)p;  p += MROW * DIMD * 4;
  ushort* qkv_bf = (ushort*)p; p += MROW * QKVN * 2;
  ushort* h_bf   = (ushort*)p; p += MROW * DIMD * 2;
  ushort* comb_bf= (ushort*)p; p += MROW * DIMD * 2;
  float* gb      = (float*)p;  p += MROW * 64 * 4;
  ushort* ckb    = (ushort*)p; p += (long)BATCH * NH * NC * DHD * 2;
  ushort* cvb    = (ushort*)p; p += (long)BATCH * NH * NC * DHD * 2;
  ushort* Vt     = (ushort*)p; p += (long)BATCH * NH * 64 * PSTRIDE * 2;
  ushort* Scb    = (ushort*)p; p += (long)BATCH * NH * NTOK * SCSTRIDE * 2;
  float* hfin    = (float*)p;  p += BATCH * DIMD * 4;
  ushort* wqkv_t = (ushort*)p; p += (long)QKVN * DIMD * 2;
  ushort* wo_t   = (ushort*)p; p += (long)DIMD * DIMD * 2;
  ushort* w1_t   = (ushort*)p; p += (long)MLPD * DIMD * 2;
  ushort* w2_t   = (ushort*)p; p += (long)DIMD * MLPD * 2;
  ushort* wg_t   = (ushort*)p; p += (long)64 * DIMD * 2;
  ushort* wkc_t  = (ushort*)p; p += (long)64 * 1024 * 2;
  ushort* wvc_t  = (ushort*)p; p += (long)64 * 1024 * 2;
  // region A: kwm+vwm (9.5 MB) aliased with P (15.4 MB) — disjoint lifetimes
  ushort* kwm    = (ushort*)p;
  ushort* vwm    = kwm + (long)BATCH * NH * NC * 1024;
  ushort* P      = kwm;
  p += (long)BATCH * NH * NTOK * PSTRIDE * 2;
  // region B: Sf (10.9 MB) aliased with ff1_bf (4.7 MB) — disjoint lifetimes
  ushort* Sf     = (ushort*)p;
  ushort* ff1_bf = Sf;
  p += (long)BATCH * NH * NTOK * SFSTRIDE * 2;

  const int M = (int)MROW;                  // 1154
  const int MB64 = (M + 63) / 64;           // 19
  const int MCK = BATCH * NH * NC;          // 2320
  const float scale = 0.125f;
  dim3 thrT(32, 8);

  patch_kernel<<<(M * DIMD + 255) / 256, 256, 0, stream>>>(img, patch_w, patch_b, pos_emb, cls_tok, x);

  for (int l = 0; l < 2; ++l) {
    const float* Wq_l  = Wq + (long)l * DIMD * DIMD;
    const float* Wk_l  = Wk + (long)l * DIMD * DIMD;
    const float* Wv_l  = Wv + (long)l * DIMD * DIMD;
    const float* Wg_l  = Wg + (long)l * DIMD * 3 * NH;
    const float* Wo_l  = Wo + (long)l * DIMD * DIMD;
    const float* kpe_l = kpe + (long)l * CBD * DHD;
    const float* vpe_l = vpe + (long)l * CBD * DHD;
    const float* Wkc_l = Wkc + (long)l * CBD * DHD * DHD;
    const float* Wvc_l = Wvc + (long)l * CBD * DHD * DHD;
    const float* w1_l  = ff_w1 + (long)l * DIMD * MLPD;
    const float* b1_l  = ff_b1 + (long)l * MLPD;
    const float* w2_l  = ff_w2 + (long)l * MLPD * DIMD;
    const float* b2_l  = ff_b2 + (long)l * DIMD;

    // all weight transposes, one dispatch
    wtrans_all_kernel<<<3232, thrT, 0, stream>>>(Wq_l, Wk_l, Wv_l, Wg_l, Wo_l, Wkc_l, Wvc_l,
                                                 w1_l, w2_l, wqkv_t, wo_t, w1_t, w2_t,
                                                 wg_t, wkc_t, wvc_t);
    // h = LN1(x) -> bf16
    ln_kernel<<<M, 256, 0, stream>>>(x, ln1_g + (long)l * DIMD, ln1_b + (long)l * DIMD, h_bf, nullptr, DIMD);
    // qkv = h @ [Wq|Wk|Wv] -> bf16
    mfma_gemm<<<dim3(QKVN / 64, MB64), 256, 0, stream>>>(h_bf, wqkv_t, nullptr, nullptr, nullptr, qkv_bf, M, QKVN, DIMD, 0);
    // gates: sigmoid(h @ Wg) (64-col padded, fp32)
    mfma_gemm<<<dim3(1, MB64), 256, 0, stream>>>(h_bf, wg_t, nullptr, nullptr, gb, nullptr, M, 64, DIMD, 2);
    // kw/vw build + ck/cv GEMMs (bf16)
    kwbuild_kernel<<<MCK, 256, 0, stream>>>(qkv_bf, kpe_l, vpe_l, kwm, vwm);
    mfma_gemm<<<dim3(1, (MCK + 63) / 64), 256, 0, stream>>>(kwm, wkc_t, nullptr, nullptr, nullptr, ckb, MCK, 64, 1024, 0);
    mfma_gemm<<<dim3(1, (MCK + 63) / 64), 256, 0, stream>>>(vwm, wvc_t, nullptr, nullptr, nullptr, cvb, MCK, 64, 1024, 0);
    // Vext^T
    vtrans_kernel<<<dim3(13, BATCH * NH), 256, 0, stream>>>(qkv_bf, cvb, Vt);
    // merged dense + compressed score GEMMs
    score_kernel<<<dim3(13, 10, BATCH * NH), 256, 0, stream>>>(qkv_bf, ckb, Sf, Scb, scale);
    // gated probability rows
    prob_kernel<<<BATCH * NH * NC, 256, 0, stream>>>(Sf, Scb, gb, P);
    // comb = P @ Vext (gates already folded)
    pv_gemm<<<dim3(10, BATCH * NH), 256, 0, stream>>>(P, Vt, comb_bf);
    // x = comb @ Wo + x
    mfma_gemm<<<dim3(DIMD / 64, MB64), 256, 0, stream>>>(comb_bf, wo_t, nullptr, x, x, nullptr, M, DIMD, DIMD, 0);
    // h = LN2(x) -> bf16
    ln_kernel<<<M, 256, 0, stream>>>(x, ln2_g + (long)l * DIMD, ln2_b + (long)l * DIMD, h_bf, nullptr, DIMD);
    // ff1 = gelu(h @ W1 + b1) -> bf16
    mfma_gemm<<<dim3(MLPD / 64, MB64), 256, 0, stream>>>(h_bf, w1_t, b1_l, nullptr, nullptr, ff1_bf, M, MLPD, DIMD, 1);
    // x = ff1 @ W2 + b2 + x
    mfma_gemm<<<dim3(DIMD / 64, MB64), 256, 0, stream>>>(ff1_bf, w2_t, b2_l, x, x, nullptr, M, DIMD, MLPD, 0);
  }

  // final: LN(x[:,0]) -> head
  ln_kernel<<<BATCH, 256, 0, stream>>>(x, hln_g, hln_b, nullptr, hfin, (long)NTOK * DIMD);
  head_kernel<<<dim3((NCLSD + 255) / 256, BATCH), 256, 0, stream>>>(hfin, head_w, head_b, out);
}